// Round 1
// baseline (1171.699 us; speedup 1.0000x reference)
//
#include <hip/hip_runtime.h>
#include <cfloat>

#define N_NODES 50000
#define N_EDGES 800000
#define E_TOT   850000
#define NG      128
#define NH      4

// ---------------- CSR build (by destination) ----------------
__global__ void count_dst_k(const int* __restrict__ ei, int* __restrict__ cnt) {
    int e = blockIdx.x * blockDim.x + threadIdx.x;
    if (e >= E_TOT) return;
    int d = (e < N_EDGES) ? ei[N_EDGES + e] : (e - N_EDGES);
    atomicAdd(&cnt[d], 1);
}

__global__ void scan_k(const int* __restrict__ cnt, int* __restrict__ row_ptr,
                       int* __restrict__ cursor) {
    __shared__ int sh[1024];
    __shared__ int carry_sh;
    if (threadIdx.x == 0) carry_sh = 0;
    __syncthreads();
    for (int base = 0; base < N_NODES; base += 1024) {
        int i = base + threadIdx.x;
        int v = (i < N_NODES) ? cnt[i] : 0;
        sh[threadIdx.x] = v;
        __syncthreads();
        for (int off = 1; off < 1024; off <<= 1) {
            int t = (threadIdx.x >= off) ? sh[threadIdx.x - off] : 0;
            __syncthreads();
            sh[threadIdx.x] += t;
            __syncthreads();
        }
        int excl = sh[threadIdx.x] - v;
        int carry = carry_sh;
        if (i < N_NODES) { int rp = carry + excl; row_ptr[i] = rp; cursor[i] = rp; }
        __syncthreads();
        if (threadIdx.x == 0) carry_sh = carry + sh[1023];
        __syncthreads();
    }
    if (threadIdx.x == 0) row_ptr[N_NODES] = carry_sh;
}

__global__ void fill_k(const int* __restrict__ ei, int* __restrict__ cursor,
                       int* __restrict__ col) {
    int e = blockIdx.x * blockDim.x + threadIdx.x;
    if (e >= E_TOT) return;
    int s, d;
    if (e < N_EDGES) { s = ei[e]; d = ei[N_EDGES + e]; }
    else { s = e - N_EDGES; d = s; }
    int slot = atomicAdd(&cursor[d], 1);
    col[slot] = s;
}

// ---------------- GEMM: out[N, NOUT] = x[N, K] @ W[K, NOUT] ----------------
// 256 threads/block = 4 waves; block does 32 rows (8 rows/wave), lanes split cols.
template<int K, int NOUT>
__global__ __launch_bounds__(256) void gemm_k(const float* __restrict__ x,
                                              const float* __restrict__ W,
                                              float* __restrict__ out) {
    constexpr int VC = NOUT / 64;  // cols per lane (2 or 4)
    __shared__ float xs[32 * K];
    int row0 = blockIdx.x * 32;
    for (int idx = threadIdx.x; idx < 32 * K / 4; idx += 256) {
        int r = (idx * 4) / K, c = (idx * 4) % K;
        float4 v = make_float4(0.f, 0.f, 0.f, 0.f);
        if (row0 + r < N_NODES) v = *(const float4*)(x + (size_t)(row0 + r) * K + c);
        *(float4*)(xs + r * K + c) = v;
    }
    __syncthreads();
    int wave = threadIdx.x >> 6, lane = threadIdx.x & 63;
    int r0 = wave * 8;
    float acc[8][VC];
    #pragma unroll
    for (int r = 0; r < 8; ++r)
        #pragma unroll
        for (int c = 0; c < VC; ++c) acc[r][c] = 0.f;
    int colb = lane * VC;
    for (int k = 0; k < K; ++k) {
        float wv[VC];
        if constexpr (VC == 4) {
            float4 t = *(const float4*)(W + (size_t)k * NOUT + colb);
            wv[0] = t.x; wv[1] = t.y; wv[2] = t.z; wv[3] = t.w;
        } else {
            float2 t = *(const float2*)(W + (size_t)k * NOUT + colb);
            wv[0] = t.x; wv[1] = t.y;
        }
        #pragma unroll
        for (int r = 0; r < 8; ++r) {
            float xv = xs[(r0 + r) * K + k];
            #pragma unroll
            for (int c = 0; c < VC; ++c) acc[r][c] += xv * wv[c];
        }
    }
    #pragma unroll
    for (int r = 0; r < 8; ++r) {
        int row = row0 + r0 + r;
        if (row < N_NODES) {
            if constexpr (VC == 4) {
                *(float4*)(out + (size_t)row * NOUT + colb) =
                    make_float4(acc[r][0], acc[r][1], acc[r][2], acc[r][3]);
            } else {
                *(float2*)(out + (size_t)row * NOUT + colb) =
                    make_float2(acc[r][0], acc[r][1]);
            }
        }
    }
}

// ---------------- per-node attention scores ----------------
template<int Fo>
__global__ void scores_k(const float* __restrict__ h, const float* __restrict__ asrc,
                         const float* __restrict__ adst, float* __restrict__ ssrc,
                         float* __restrict__ sdst) {
    constexpr int HFo = NH * Fo;
    int n = blockIdx.x, t = threadIdx.x;  // blockDim = HFo
    float v = h[(size_t)n * HFo + t];
    float ps = v * asrc[t], pd = v * adst[t];
    #pragma unroll
    for (int off = Fo >> 1; off; off >>= 1) {
        ps += __shfl_xor(ps, off);
        pd += __shfl_xor(pd, off);
    }
    if ((t & (Fo - 1)) == 0) {
        int hd = t / Fo;
        ssrc[n * NH + hd] = ps;
        sdst[n * NH + hd] = pd;
    }
}

// ---------------- edge-softmax + aggregation (one block per dst node) ----------------
template<int Fo>
__global__ void agg_k(const float* __restrict__ h, const float* __restrict__ ssrc,
                      const float* __restrict__ sdst, const int* __restrict__ row_ptr,
                      const int* __restrict__ col, const float* __restrict__ bias,
                      float* __restrict__ out) {
    constexpr int HFo = NH * Fo;
    int v = blockIdx.x, t = threadIdx.x;  // blockDim = HFo
    int hd = t / Fo, lg = t & (Fo - 1);
    int beg = row_ptr[v], end = row_ptr[v + 1];
    float sdv = sdst[v * NH + hd];
    // phase 1: exact segment max per head (edge-parallel within head group)
    float m = -FLT_MAX;
    for (int j = beg + lg; j < end; j += Fo) {
        int u = col[j];
        float e = ssrc[u * NH + hd] + sdv;
        e = (e > 0.f) ? e : 0.2f * e;
        m = fmaxf(m, e);
    }
    #pragma unroll
    for (int off = Fo >> 1; off; off >>= 1) m = fmaxf(m, __shfl_xor(m, off));
    // phase 2: sequential over incident edges, feature-parallel across block
    float acc = 0.f, den = 0.f;
    for (int j = beg; j < end; ++j) {
        int u = col[j];
        float e = ssrc[u * NH + hd] + sdv;
        e = (e > 0.f) ? e : 0.2f * e;
        float ex = __expf(e - m);
        den += ex;
        acc += ex * h[(size_t)u * HFo + t];
    }
    out[(size_t)v * HFo + t] = fmaxf(acc / (den + 1e-16f) + bias[t], 0.f);
}

// ---------------- pooling (batch_index is sorted -> run-length pre-agg) ----------------
__global__ void pool_k(const float* __restrict__ h, const int* __restrict__ batch,
                       float* __restrict__ gsum, float* __restrict__ gmax) {
    int f = threadIdx.x;  // 256
    int n0 = blockIdx.x * 32;
    int nend = min(n0 + 32, N_NODES);
    int cur = -1;
    float sa = 0.f, ma = 0.f;
    for (int n = n0; n < nend; ++n) {
        int g = batch[n];
        float val = h[(size_t)n * 256 + f];
        if (g != cur) {
            if (cur >= 0) {
                atomicAdd(&gsum[cur * 256 + f], sa);
                atomicMax((int*)&gmax[cur * 256 + f], __float_as_int(ma));  // vals >= 0
            }
            cur = g; sa = 0.f; ma = 0.f;
        }
        sa += val;
        ma = fmaxf(ma, val);
    }
    if (cur >= 0) {
        atomicAdd(&gsum[cur * 256 + f], sa);
        atomicMax((int*)&gmax[cur * 256 + f], __float_as_int(ma));
    }
}

__global__ void cnt_k(const int* __restrict__ batch, int* __restrict__ gcnt) {
    int n = blockIdx.x * blockDim.x + threadIdx.x;
    if (n < N_NODES) atomicAdd(&gcnt[batch[n]], 1);
}

__global__ void readout_k(const float* __restrict__ gsum, const float* __restrict__ gmax,
                          const int* __restrict__ gcnt, const float* __restrict__ Wout,
                          const float* __restrict__ bout, float* __restrict__ out) {
    int g = blockIdx.x, lane = threadIdx.x;  // 128 blocks x 64 threads
    float inv = 1.f / fmaxf((float)gcnt[g], 1.f);
    float acc[10];
    #pragma unroll
    for (int j = 0; j < 10; ++j) acc[j] = 0.f;
    for (int f = lane; f < 512; f += 64) {
        float p = (f < 256) ? gsum[g * 256 + f] * inv : gmax[g * 256 + (f - 256)];
        #pragma unroll
        for (int j = 0; j < 10; ++j) acc[j] += p * Wout[f * 10 + j];
    }
    #pragma unroll
    for (int j = 0; j < 10; ++j) {
        float a = acc[j];
        #pragma unroll
        for (int off = 32; off; off >>= 1) a += __shfl_xor(a, off);
        if (lane == 0) out[g * 10 + j] = a + bout[j];
    }
}

extern "C" void kernel_launch(void* const* d_in, const int* in_sizes, int n_in,
                              void* d_out, int out_size, void* d_ws, size_t ws_size,
                              hipStream_t stream) {
    const float* x    = (const float*)d_in[0];
    const int*   ei   = (const int*)d_in[1];
    const int*   batch= (const int*)d_in[2];
    const float* W0   = (const float*)d_in[3];
    const float* as0  = (const float*)d_in[4];
    const float* ad0  = (const float*)d_in[5];
    const float* b0   = (const float*)d_in[6];
    const float* W1   = (const float*)d_in[7];
    const float* as1  = (const float*)d_in[8];
    const float* ad1  = (const float*)d_in[9];
    const float* b1   = (const float*)d_in[10];
    const float* W2   = (const float*)d_in[11];
    const float* as2  = (const float*)d_in[12];
    const float* ad2  = (const float*)d_in[13];
    const float* b2   = (const float*)d_in[14];
    const float* Wout = (const float*)d_in[15];
    const float* bout = (const float*)d_in[16];
    float* out = (float*)d_out;

    char* ws = (char*)d_ws;
    size_t o = 0;
    auto take = [&](size_t bytes) { size_t r = o; o += (bytes + 255) & ~(size_t)255; return r; };
    size_t cnt_o  = take((size_t)N_NODES * 4);
    size_t gsum_o = take((size_t)NG * 256 * 4);
    size_t gmax_o = take((size_t)NG * 256 * 4);
    size_t gcnt_o = take((size_t)NG * 4);
    size_t zero_bytes = o;                       // everything above needs zero-init
    size_t rp_o   = take((size_t)(N_NODES + 1) * 4);
    size_t cur_o  = take((size_t)N_NODES * 4);
    size_t col_o  = take((size_t)E_TOT * 4);
    size_t ssrc_o = take((size_t)N_NODES * NH * 4);
    size_t sdst_o = take((size_t)N_NODES * NH * 4);
    size_t bufA_o = take((size_t)N_NODES * 256 * 4);
    size_t bufB_o = take((size_t)N_NODES * 256 * 4);

    int*   cnt    = (int*)(ws + cnt_o);
    float* gsum   = (float*)(ws + gsum_o);
    float* gmax   = (float*)(ws + gmax_o);
    int*   gcnt   = (int*)(ws + gcnt_o);
    int*   row_ptr= (int*)(ws + rp_o);
    int*   cursor = (int*)(ws + cur_o);
    int*   col    = (int*)(ws + col_o);
    float* ssrc   = (float*)(ws + ssrc_o);
    float* sdst   = (float*)(ws + sdst_o);
    float* bufA   = (float*)(ws + bufA_o);
    float* bufB   = (float*)(ws + bufB_o);

    hipMemsetAsync(ws, 0, zero_bytes, stream);

    count_dst_k<<<(E_TOT + 255) / 256, 256, 0, stream>>>(ei, cnt);
    scan_k<<<1, 1024, 0, stream>>>(cnt, row_ptr, cursor);
    fill_k<<<(E_TOT + 255) / 256, 256, 0, stream>>>(ei, cursor, col);

    // layer 0: 128 -> H4*Fo32 (128)
    gemm_k<128, 128><<<(N_NODES + 31) / 32, 256, 0, stream>>>(x, W0, bufA);
    scores_k<32><<<N_NODES, 128, 0, stream>>>(bufA, as0, ad0, ssrc, sdst);
    agg_k<32><<<N_NODES, 128, 0, stream>>>(bufA, ssrc, sdst, row_ptr, col, b0, bufB);

    // layer 1: 128 -> H4*Fo64 (256)
    gemm_k<128, 256><<<(N_NODES + 31) / 32, 256, 0, stream>>>(bufB, W1, bufA);
    scores_k<64><<<N_NODES, 256, 0, stream>>>(bufA, as1, ad1, ssrc, sdst);
    agg_k<64><<<N_NODES, 256, 0, stream>>>(bufA, ssrc, sdst, row_ptr, col, b1, bufB);

    // layer 2: 256 -> H4*Fo64 (256)
    gemm_k<256, 256><<<(N_NODES + 31) / 32, 256, 0, stream>>>(bufB, W2, bufA);
    scores_k<64><<<N_NODES, 256, 0, stream>>>(bufA, as2, ad2, ssrc, sdst);
    agg_k<64><<<N_NODES, 256, 0, stream>>>(bufA, ssrc, sdst, row_ptr, col, b2, bufB);

    // pooling + readout
    pool_k<<<(N_NODES + 31) / 32, 256, 0, stream>>>(bufB, batch, gsum, gmax);
    cnt_k<<<(N_NODES + 255) / 256, 256, 0, stream>>>(batch, gcnt);
    readout_k<<<NG, 64, 0, stream>>>(gsum, gmax, gcnt, Wout, bout, out);
}

// Round 2
// 938.233 us; speedup vs baseline: 1.2488x; 1.2488x over previous
//
#include <hip/hip_runtime.h>
#include <cfloat>

#define N_NODES 50000
#define N_EDGES 800000
#define E_TOT   850000
#define NG      128
#define NH      4
#define CAP     96   // max in-degree handled by fast path (Poisson(16)+self-loop; P(>96) ~ 0)

// ---------------- CSR build (by destination) ----------------
__global__ void count_dst_k(const int* __restrict__ ei, int* __restrict__ cnt) {
    int e = blockIdx.x * blockDim.x + threadIdx.x;
    if (e >= E_TOT) return;
    int d = (e < N_EDGES) ? ei[N_EDGES + e] : (e - N_EDGES);
    atomicAdd(&cnt[d], 1);
}

// single-block scan, shfl-based (3 barriers/tile instead of ~20)
__global__ void scan_k(const int* __restrict__ cnt, int* __restrict__ row_ptr,
                       int* __restrict__ cursor) {
    __shared__ int wsum[16];
    __shared__ int carry_sh;
    int lane = threadIdx.x & 63, wv = threadIdx.x >> 6;
    if (threadIdx.x == 0) carry_sh = 0;
    __syncthreads();
    for (int base = 0; base < N_NODES; base += 1024) {
        int i = base + threadIdx.x;
        int v = (i < N_NODES) ? cnt[i] : 0;
        int s = v;  // inclusive wave scan
        #pragma unroll
        for (int off = 1; off < 64; off <<= 1) {
            int t = __shfl_up(s, off);
            if (lane >= off) s += t;
        }
        if (lane == 63) wsum[wv] = s;
        __syncthreads();
        if (wv == 0 && lane < 16) {
            int ws = wsum[lane];
            #pragma unroll
            for (int off = 1; off < 16; off <<= 1) {
                int t = __shfl_up(ws, off);
                if (lane >= off) ws += t;
            }
            wsum[lane] = ws;  // inclusive across waves
        }
        __syncthreads();
        int carry = carry_sh;
        int woff = wv ? wsum[wv - 1] : 0;
        if (i < N_NODES) {
            int rp = carry + woff + s - v;
            row_ptr[i] = rp; cursor[i] = rp;
        }
        __syncthreads();
        if (threadIdx.x == 0) carry_sh = carry + wsum[15];
        __syncthreads();
    }
    if (threadIdx.x == 0) row_ptr[N_NODES] = carry_sh;
}

__global__ void fill_k(const int* __restrict__ ei, int* __restrict__ cursor,
                       int* __restrict__ col) {
    int e = blockIdx.x * blockDim.x + threadIdx.x;
    if (e >= E_TOT) return;
    int s, d;
    if (e < N_EDGES) { s = ei[e]; d = ei[N_EDGES + e]; }
    else { s = e - N_EDGES; d = s; }
    int slot = atomicAdd(&cursor[d], 1);
    col[slot] = s;
}

// ---------------- GEMM: out[N, NOUT] = x[N, K] @ W[K, NOUT] ----------------
template<int K, int NOUT>
__global__ __launch_bounds__(256) void gemm_k(const float* __restrict__ x,
                                              const float* __restrict__ W,
                                              float* __restrict__ out) {
    constexpr int VC = NOUT / 64;  // cols per lane (2 or 4)
    __shared__ float xs[32 * K];
    int row0 = blockIdx.x * 32;
    for (int idx = threadIdx.x; idx < 32 * K / 4; idx += 256) {
        int r = (idx * 4) / K, c = (idx * 4) % K;
        float4 v = make_float4(0.f, 0.f, 0.f, 0.f);
        if (row0 + r < N_NODES) v = *(const float4*)(x + (size_t)(row0 + r) * K + c);
        *(float4*)(xs + r * K + c) = v;
    }
    __syncthreads();
    int wave = threadIdx.x >> 6, lane = threadIdx.x & 63;
    int r0 = wave * 8;
    float acc[8][VC];
    #pragma unroll
    for (int r = 0; r < 8; ++r)
        #pragma unroll
        for (int c = 0; c < VC; ++c) acc[r][c] = 0.f;
    int colb = lane * VC;
    for (int k = 0; k < K; ++k) {
        float wv[VC];
        if constexpr (VC == 4) {
            float4 t = *(const float4*)(W + (size_t)k * NOUT + colb);
            wv[0] = t.x; wv[1] = t.y; wv[2] = t.z; wv[3] = t.w;
        } else {
            float2 t = *(const float2*)(W + (size_t)k * NOUT + colb);
            wv[0] = t.x; wv[1] = t.y;
        }
        #pragma unroll
        for (int r = 0; r < 8; ++r) {
            float xv = xs[(r0 + r) * K + k];
            #pragma unroll
            for (int c = 0; c < VC; ++c) acc[r][c] += xv * wv[c];
        }
    }
    #pragma unroll
    for (int r = 0; r < 8; ++r) {
        int row = row0 + r0 + r;
        if (row < N_NODES) {
            if constexpr (VC == 4) {
                *(float4*)(out + (size_t)row * NOUT + colb) =
                    make_float4(acc[r][0], acc[r][1], acc[r][2], acc[r][3]);
            } else {
                *(float2*)(out + (size_t)row * NOUT + colb) =
                    make_float2(acc[r][0], acc[r][1]);
            }
        }
    }
}

// ---------------- per-node attention scores ----------------
template<int Fo>
__global__ void scores_k(const float* __restrict__ h, const float* __restrict__ asrc,
                         const float* __restrict__ adst, float* __restrict__ ssrc,
                         float* __restrict__ sdst) {
    constexpr int HFo = NH * Fo;
    int n = blockIdx.x, t = threadIdx.x;  // blockDim = HFo
    float v = h[(size_t)n * HFo + t];
    float ps = v * asrc[t], pd = v * adst[t];
    #pragma unroll
    for (int off = Fo >> 1; off; off >>= 1) {
        ps += __shfl_xor(ps, off);
        pd += __shfl_xor(pd, off);
    }
    if ((t & (Fo - 1)) == 0) {
        int hd = t / Fo;
        ssrc[n * NH + hd] = ps;
        sdst[n * NH + hd] = pd;
    }
}

// ---------------- edge-softmax + aggregation (one block per dst node) ----------------
// Fast path (deg <= CAP): col + pre-activation scores staged in LDS; the
// accumulate loop then has only independent h-row gathers, unrolled x4.
template<int Fo>
__global__ void agg_k(const float* __restrict__ h, const float* __restrict__ ssrc,
                      const float* __restrict__ sdst, const int* __restrict__ row_ptr,
                      const int* __restrict__ col, const float* __restrict__ bias,
                      float* __restrict__ out) {
    constexpr int HFo = NH * Fo;
    __shared__ int   colL[CAP];
    __shared__ float ew[NH][CAP + 1];
    int v = blockIdx.x, t = threadIdx.x;  // blockDim = HFo
    int hd = t / Fo, lg = t & (Fo - 1);
    int beg = row_ptr[v], end = row_ptr[v + 1];
    int cnt = end - beg;
    float sdv = sdst[v * NH + hd];

    if (cnt <= CAP) {
        // stage edge list
        if (t < cnt) colL[t] = col[beg + t];
        __syncthreads();
        // per-head pre-activation scores -> LDS (head groups in parallel)
        for (int j = lg; j < cnt; j += Fo) {
            int u = colL[j];
            float e = ssrc[u * NH + hd] + sdv;
            ew[hd][j] = (e > 0.f) ? e : 0.2f * e;
        }
        __syncthreads();
        // exact per-head max (strided + shfl reduce within the Fo-lane group)
        float m = -FLT_MAX;
        for (int j = lg; j < cnt; j += Fo) m = fmaxf(m, ew[hd][j]);
        #pragma unroll
        for (int off = Fo >> 1; off; off >>= 1) m = fmaxf(m, __shfl_xor(m, off));
        // accumulate: independent gathers, 4-deep MLP
        float acc = 0.f, den = 0.f;
        int j = 0;
        for (; j + 3 < cnt; j += 4) {
            int u0 = colL[j], u1 = colL[j + 1], u2 = colL[j + 2], u3 = colL[j + 3];
            float w0 = __expf(ew[hd][j]     - m);
            float w1 = __expf(ew[hd][j + 1] - m);
            float w2 = __expf(ew[hd][j + 2] - m);
            float w3 = __expf(ew[hd][j + 3] - m);
            float v0 = h[(size_t)u0 * HFo + t];
            float v1 = h[(size_t)u1 * HFo + t];
            float v2 = h[(size_t)u2 * HFo + t];
            float v3 = h[(size_t)u3 * HFo + t];
            den += (w0 + w1) + (w2 + w3);
            acc += w0 * v0 + w1 * v1 + w2 * v2 + w3 * v3;
        }
        for (; j < cnt; ++j) {
            int u = colL[j];
            float w = __expf(ew[hd][j] - m);
            den += w;
            acc += w * h[(size_t)u * HFo + t];
        }
        out[(size_t)v * HFo + t] = fmaxf(acc / (den + 1e-16f) + bias[t], 0.f);
    } else {
        // slow path (essentially never taken): streaming, exact
        float m = -FLT_MAX;
        for (int j = beg + lg; j < end; j += Fo) {
            int u = col[j];
            float e = ssrc[u * NH + hd] + sdv;
            e = (e > 0.f) ? e : 0.2f * e;
            m = fmaxf(m, e);
        }
        #pragma unroll
        for (int off = Fo >> 1; off; off >>= 1) m = fmaxf(m, __shfl_xor(m, off));
        float acc = 0.f, den = 0.f;
        for (int j = beg; j < end; ++j) {
            int u = col[j];
            float e = ssrc[u * NH + hd] + sdv;
            e = (e > 0.f) ? e : 0.2f * e;
            float ex = __expf(e - m);
            den += ex;
            acc += ex * h[(size_t)u * HFo + t];
        }
        out[(size_t)v * HFo + t] = fmaxf(acc / (den + 1e-16f) + bias[t], 0.f);
    }
}

// ---------------- pooling (batch_index is sorted -> run-length pre-agg) ----------------
__global__ void pool_k(const float* __restrict__ h, const int* __restrict__ batch,
                       float* __restrict__ gsum, float* __restrict__ gmax) {
    int f = threadIdx.x;  // 256
    int n0 = blockIdx.x * 32;
    int nend = min(n0 + 32, N_NODES);
    int cur = -1;
    float sa = 0.f, ma = 0.f;
    for (int n = n0; n < nend; ++n) {
        int g = batch[n];
        float val = h[(size_t)n * 256 + f];
        if (g != cur) {
            if (cur >= 0) {
                atomicAdd(&gsum[cur * 256 + f], sa);
                atomicMax((int*)&gmax[cur * 256 + f], __float_as_int(ma));  // vals >= 0
            }
            cur = g; sa = 0.f; ma = 0.f;
        }
        sa += val;
        ma = fmaxf(ma, val);
    }
    if (cur >= 0) {
        atomicAdd(&gsum[cur * 256 + f], sa);
        atomicMax((int*)&gmax[cur * 256 + f], __float_as_int(ma));
    }
}

__global__ void cnt_k(const int* __restrict__ batch, int* __restrict__ gcnt) {
    int n = blockIdx.x * blockDim.x + threadIdx.x;
    if (n < N_NODES) atomicAdd(&gcnt[batch[n]], 1);
}

__global__ void readout_k(const float* __restrict__ gsum, const float* __restrict__ gmax,
                          const int* __restrict__ gcnt, const float* __restrict__ Wout,
                          const float* __restrict__ bout, float* __restrict__ out) {
    int g = blockIdx.x, lane = threadIdx.x;  // 128 blocks x 64 threads
    float inv = 1.f / fmaxf((float)gcnt[g], 1.f);
    float acc[10];
    #pragma unroll
    for (int j = 0; j < 10; ++j) acc[j] = 0.f;
    for (int f = lane; f < 512; f += 64) {
        float p = (f < 256) ? gsum[g * 256 + f] * inv : gmax[g * 256 + (f - 256)];
        #pragma unroll
        for (int j = 0; j < 10; ++j) acc[j] += p * Wout[f * 10 + j];
    }
    #pragma unroll
    for (int j = 0; j < 10; ++j) {
        float a = acc[j];
        #pragma unroll
        for (int off = 32; off; off >>= 1) a += __shfl_xor(a, off);
        if (lane == 0) out[g * 10 + j] = a + bout[j];
    }
}

extern "C" void kernel_launch(void* const* d_in, const int* in_sizes, int n_in,
                              void* d_out, int out_size, void* d_ws, size_t ws_size,
                              hipStream_t stream) {
    const float* x    = (const float*)d_in[0];
    const int*   ei   = (const int*)d_in[1];
    const int*   batch= (const int*)d_in[2];
    const float* W0   = (const float*)d_in[3];
    const float* as0  = (const float*)d_in[4];
    const float* ad0  = (const float*)d_in[5];
    const float* b0   = (const float*)d_in[6];
    const float* W1   = (const float*)d_in[7];
    const float* as1  = (const float*)d_in[8];
    const float* ad1  = (const float*)d_in[9];
    const float* b1   = (const float*)d_in[10];
    const float* W2   = (const float*)d_in[11];
    const float* as2  = (const float*)d_in[12];
    const float* ad2  = (const float*)d_in[13];
    const float* b2   = (const float*)d_in[14];
    const float* Wout = (const float*)d_in[15];
    const float* bout = (const float*)d_in[16];
    float* out = (float*)d_out;

    char* ws = (char*)d_ws;
    size_t o = 0;
    auto take = [&](size_t bytes) { size_t r = o; o += (bytes + 255) & ~(size_t)255; return r; };
    size_t cnt_o  = take((size_t)N_NODES * 4);
    size_t gsum_o = take((size_t)NG * 256 * 4);
    size_t gmax_o = take((size_t)NG * 256 * 4);
    size_t gcnt_o = take((size_t)NG * 4);
    size_t zero_bytes = o;                       // everything above needs zero-init
    size_t rp_o   = take((size_t)(N_NODES + 1) * 4);
    size_t cur_o  = take((size_t)N_NODES * 4);
    size_t col_o  = take((size_t)E_TOT * 4);
    size_t ssrc_o = take((size_t)N_NODES * NH * 4);
    size_t sdst_o = take((size_t)N_NODES * NH * 4);
    size_t bufA_o = take((size_t)N_NODES * 256 * 4);
    size_t bufB_o = take((size_t)N_NODES * 256 * 4);

    int*   cnt    = (int*)(ws + cnt_o);
    float* gsum   = (float*)(ws + gsum_o);
    float* gmax   = (float*)(ws + gmax_o);
    int*   gcnt   = (int*)(ws + gcnt_o);
    int*   row_ptr= (int*)(ws + rp_o);
    int*   cursor = (int*)(ws + cur_o);
    int*   col    = (int*)(ws + col_o);
    float* ssrc   = (float*)(ws + ssrc_o);
    float* sdst   = (float*)(ws + sdst_o);
    float* bufA   = (float*)(ws + bufA_o);
    float* bufB   = (float*)(ws + bufB_o);

    hipMemsetAsync(ws, 0, zero_bytes, stream);

    count_dst_k<<<(E_TOT + 255) / 256, 256, 0, stream>>>(ei, cnt);
    scan_k<<<1, 1024, 0, stream>>>(cnt, row_ptr, cursor);
    fill_k<<<(E_TOT + 255) / 256, 256, 0, stream>>>(ei, cursor, col);

    // layer 0: 128 -> H4*Fo32 (128)
    gemm_k<128, 128><<<(N_NODES + 31) / 32, 256, 0, stream>>>(x, W0, bufA);
    scores_k<32><<<N_NODES, 128, 0, stream>>>(bufA, as0, ad0, ssrc, sdst);
    agg_k<32><<<N_NODES, 128, 0, stream>>>(bufA, ssrc, sdst, row_ptr, col, b0, bufB);

    // layer 1: 128 -> H4*Fo64 (256)
    gemm_k<128, 256><<<(N_NODES + 31) / 32, 256, 0, stream>>>(bufB, W1, bufA);
    scores_k<64><<<N_NODES, 256, 0, stream>>>(bufA, as1, ad1, ssrc, sdst);
    agg_k<64><<<N_NODES, 256, 0, stream>>>(bufA, ssrc, sdst, row_ptr, col, b1, bufB);

    // layer 2: 256 -> H4*Fo64 (256)
    gemm_k<256, 256><<<(N_NODES + 31) / 32, 256, 0, stream>>>(bufB, W2, bufA);
    scores_k<64><<<N_NODES, 256, 0, stream>>>(bufA, as2, ad2, ssrc, sdst);
    agg_k<64><<<N_NODES, 256, 0, stream>>>(bufA, ssrc, sdst, row_ptr, col, b2, bufB);

    // pooling + readout
    pool_k<<<(N_NODES + 31) / 32, 256, 0, stream>>>(bufB, batch, gsum, gmax);
    cnt_k<<<(N_NODES + 255) / 256, 256, 0, stream>>>(batch, gcnt);
    readout_k<<<NG, 64, 0, stream>>>(bufB == bufB ? gsum : gsum, gmax, gcnt, Wout, bout, out);
}

// Round 3
// 878.780 us; speedup vs baseline: 1.3333x; 1.0677x over previous
//
#include <hip/hip_runtime.h>
#include <cfloat>

#define N_NODES 50000
#define N_EDGES 800000
#define E_TOT   850000
#define NG      128
#define NH      4
#define CAP     96   // fast-path max in-degree (Poisson(16)+self-loop; max ~50)

// ---------------- CSR build (by destination) ----------------
__global__ void count_dst_k(const int* __restrict__ ei, int* __restrict__ cnt) {
    int e = blockIdx.x * blockDim.x + threadIdx.x;
    if (e >= E_TOT) return;
    int d = (e < N_EDGES) ? ei[N_EDGES + e] : (e - N_EDGES);
    atomicAdd(&cnt[d], 1);
}

__global__ void scan_k(const int* __restrict__ cnt, int* __restrict__ row_ptr,
                       int* __restrict__ cursor) {
    __shared__ int wsum[16];
    __shared__ int carry_sh;
    int lane = threadIdx.x & 63, wv = threadIdx.x >> 6;
    if (threadIdx.x == 0) carry_sh = 0;
    __syncthreads();
    for (int base = 0; base < N_NODES; base += 1024) {
        int i = base + threadIdx.x;
        int v = (i < N_NODES) ? cnt[i] : 0;
        int s = v;
        #pragma unroll
        for (int off = 1; off < 64; off <<= 1) {
            int t = __shfl_up(s, off);
            if (lane >= off) s += t;
        }
        if (lane == 63) wsum[wv] = s;
        __syncthreads();
        if (wv == 0 && lane < 16) {
            int ws = wsum[lane];
            #pragma unroll
            for (int off = 1; off < 16; off <<= 1) {
                int t = __shfl_up(ws, off);
                if (lane >= off) ws += t;
            }
            wsum[lane] = ws;
        }
        __syncthreads();
        int carry = carry_sh;
        int woff = wv ? wsum[wv - 1] : 0;
        if (i < N_NODES) {
            int rp = carry + woff + s - v;
            row_ptr[i] = rp; cursor[i] = rp;
        }
        __syncthreads();
        if (threadIdx.x == 0) carry_sh = carry + wsum[15];
        __syncthreads();
    }
    if (threadIdx.x == 0) row_ptr[N_NODES] = carry_sh;
}

__global__ void fill_k(const int* __restrict__ ei, int* __restrict__ cursor,
                       int* __restrict__ col) {
    int e = blockIdx.x * blockDim.x + threadIdx.x;
    if (e >= E_TOT) return;
    int s, d;
    if (e < N_EDGES) { s = ei[e]; d = ei[N_EDGES + e]; }
    else { s = e - N_EDGES; d = s; }
    int slot = atomicAdd(&cursor[d], 1);
    col[slot] = s;
}

// ---------------- GEMM + fused attention scores ----------------
// out[N,NOUT] = x[N,K] @ W[K,NOUT]; ssrc/sdst[n,h] = dot(out_row, a_src/a_dst)
// 256 threads; 32 rows/block, 8 rows/wave; ds_read_b128 for x (4 k's/read).
template<int K, int NOUT>
__global__ __launch_bounds__(256) void gemm_k(const float* __restrict__ x,
                                              const float* __restrict__ W,
                                              const float* __restrict__ asrc,
                                              const float* __restrict__ adst,
                                              float* __restrict__ out,
                                              float* __restrict__ ssrc,
                                              float* __restrict__ sdst) {
    constexpr int VC = NOUT / 64;  // cols per lane (2 or 4)
    __shared__ float xs[32 * K];
    int row0 = blockIdx.x * 32;
    for (int idx = threadIdx.x; idx < 32 * K / 4; idx += 256) {
        int r = (idx * 4) / K, c = (idx * 4) % K;
        float4 v = make_float4(0.f, 0.f, 0.f, 0.f);
        if (row0 + r < N_NODES) v = *(const float4*)(x + (size_t)(row0 + r) * K + c);
        *(float4*)(xs + r * K + c) = v;
    }
    __syncthreads();
    int wave = threadIdx.x >> 6, lane = threadIdx.x & 63;
    int r0 = wave * 8;
    float acc[8][VC];
    #pragma unroll
    for (int r = 0; r < 8; ++r)
        #pragma unroll
        for (int c = 0; c < VC; ++c) acc[r][c] = 0.f;
    int colb = lane * VC;
    for (int k = 0; k < K; k += 4) {
        float4 xr[8];
        #pragma unroll
        for (int r = 0; r < 8; ++r) xr[r] = *(const float4*)(xs + (r0 + r) * K + k);
        #pragma unroll
        for (int kk = 0; kk < 4; ++kk) {
            float wv[VC];
            if constexpr (VC == 4) {
                float4 t = *(const float4*)(W + (size_t)(k + kk) * NOUT + colb);
                wv[0] = t.x; wv[1] = t.y; wv[2] = t.z; wv[3] = t.w;
            } else {
                float2 t = *(const float2*)(W + (size_t)(k + kk) * NOUT + colb);
                wv[0] = t.x; wv[1] = t.y;
            }
            #pragma unroll
            for (int r = 0; r < 8; ++r) {
                float xv = (kk == 0) ? xr[r].x : (kk == 1) ? xr[r].y
                         : (kk == 2) ? xr[r].z : xr[r].w;
                #pragma unroll
                for (int c = 0; c < VC; ++c) acc[r][c] += xv * wv[c];
            }
        }
    }
    // epilogue: store h rows + fused scores (head = colb/Fo = lane/16 for both shapes)
    float avs[VC], avd[VC];
    #pragma unroll
    for (int c = 0; c < VC; ++c) { avs[c] = asrc[colb + c]; avd[c] = adst[colb + c]; }
    int hd = lane >> 4, lg = lane & 15;
    #pragma unroll
    for (int r = 0; r < 8; ++r) {
        int row = row0 + r0 + r;
        if (row < N_NODES) {
            if constexpr (VC == 4) {
                *(float4*)(out + (size_t)row * NOUT + colb) =
                    make_float4(acc[r][0], acc[r][1], acc[r][2], acc[r][3]);
            } else {
                *(float2*)(out + (size_t)row * NOUT + colb) =
                    make_float2(acc[r][0], acc[r][1]);
            }
            float ps = 0.f, pd = 0.f;
            #pragma unroll
            for (int c = 0; c < VC; ++c) { ps += acc[r][c] * avs[c]; pd += acc[r][c] * avd[c]; }
            #pragma unroll
            for (int off = 1; off < 16; off <<= 1) {
                ps += __shfl_xor(ps, off);
                pd += __shfl_xor(pd, off);
            }
            if (lg == 0) {
                ssrc[row * NH + hd] = ps;
                sdst[row * NH + hd] = pd;
            }
        }
    }
}

// ---------------- edge-softmax + aggregation: ONE WAVE PER NODE ----------------
// block = 256 = 4 waves = 4 nodes; wave-private LDS slices, no __syncthreads.
// Lane owns VF consecutive features (float4/float2 gathers); 16-lane groups = heads.
template<int Fo>
__global__ __launch_bounds__(256) void agg_k(const float* __restrict__ h,
                                             const float* __restrict__ ssrc,
                                             const float* __restrict__ sdst,
                                             const int* __restrict__ row_ptr,
                                             const int* __restrict__ col,
                                             const float* __restrict__ bias,
                                             float* __restrict__ out) {
    constexpr int HFo = NH * Fo;
    constexpr int VF = Fo / 16;  // 4 (Fo=64) or 2 (Fo=32)
    typedef float vf_t __attribute__((ext_vector_type(VF)));
    __shared__ int   colL[4][CAP];
    __shared__ float aw[4][NH][CAP + 1];
    int wv = threadIdx.x >> 6, lane = threadIdx.x & 63;
    int v = blockIdx.x * 4 + wv;
    if (v >= N_NODES) return;
    int hd = lane >> 4, lg = lane & 15;  // head group: 16 lanes
    int beg = row_ptr[v], cnt = row_ptr[v + 1] - beg;
    float sdv = sdst[v * NH + hd];
    int f0 = lane * VF;  // f0/Fo == lane/16 == hd for both shapes

    if (cnt <= CAP) {
        for (int j = lane; j < cnt; j += 64) colL[wv][j] = col[beg + j];
        __builtin_amdgcn_wave_barrier();
        // per-head pre-activation scores + exact max (strided over 16-lane group)
        float m = -FLT_MAX;
        for (int j = lg; j < cnt; j += 16) {
            int u = colL[wv][j];
            float e = ssrc[u * NH + hd] + sdv;
            e = (e > 0.f) ? e : 0.2f * e;
            aw[wv][hd][j] = e;
            m = fmaxf(m, e);
        }
        #pragma unroll
        for (int off = 1; off < 16; off <<= 1) m = fmaxf(m, __shfl_xor(m, off));
        __builtin_amdgcn_wave_barrier();
        // w = exp(e-m) once per (head, edge); den via group shfl-reduce
        float den = 0.f;
        for (int j = lg; j < cnt; j += 16) {
            float wj = __expf(aw[wv][hd][j] - m);
            aw[wv][hd][j] = wj;
            den += wj;
        }
        #pragma unroll
        for (int off = 1; off < 16; off <<= 1) den += __shfl_xor(den, off);
        float inv = 1.f / (den + 1e-16f);
        __builtin_amdgcn_wave_barrier();
        // gather: 1 vector load per edge per wave, unroll x4
        vf_t acc = {};
        int j = 0;
        for (; j + 4 <= cnt; j += 4) {
            int u0 = colL[wv][j],     u1 = colL[wv][j + 1];
            int u2 = colL[wv][j + 2], u3 = colL[wv][j + 3];
            float w0 = aw[wv][hd][j],     w1 = aw[wv][hd][j + 1];
            float w2 = aw[wv][hd][j + 2], w3 = aw[wv][hd][j + 3];
            vf_t h0 = *(const vf_t*)(h + (size_t)u0 * HFo + f0);
            vf_t h1 = *(const vf_t*)(h + (size_t)u1 * HFo + f0);
            vf_t h2 = *(const vf_t*)(h + (size_t)u2 * HFo + f0);
            vf_t h3 = *(const vf_t*)(h + (size_t)u3 * HFo + f0);
            acc += w0 * h0;
            acc += w1 * h1;
            acc += w2 * h2;
            acc += w3 * h3;
        }
        for (; j < cnt; ++j) {
            int u = colL[wv][j];
            float wj = aw[wv][hd][j];
            vf_t hv = *(const vf_t*)(h + (size_t)u * HFo + f0);
            acc += wj * hv;
        }
        vf_t bv = *(const vf_t*)(bias + f0);
        vf_t res = acc * inv + bv;
        #pragma unroll
        for (int c = 0; c < VF; ++c) res[c] = fmaxf(res[c], 0.f);
        *(vf_t*)(out + (size_t)v * HFo + f0) = res;
    } else {
        // slow path (practically never): streaming, exact
        float m = -FLT_MAX;
        for (int j = lg; j < cnt; j += 16) {
            int u = col[beg + j];
            float e = ssrc[u * NH + hd] + sdv;
            e = (e > 0.f) ? e : 0.2f * e;
            m = fmaxf(m, e);
        }
        #pragma unroll
        for (int off = 1; off < 16; off <<= 1) m = fmaxf(m, __shfl_xor(m, off));
        float den = 0.f;
        vf_t acc = {};
        for (int j = 0; j < cnt; ++j) {
            int u = col[beg + j];
            float e = ssrc[u * NH + hd] + sdv;
            e = (e > 0.f) ? e : 0.2f * e;
            float wj = __expf(e - m);
            den += wj;
            vf_t hv = *(const vf_t*)(h + (size_t)u * HFo + f0);
            acc += wj * hv;
        }
        float inv = 1.f / (den + 1e-16f);
        vf_t bv = *(const vf_t*)(bias + f0);
        vf_t res = acc * inv + bv;
        #pragma unroll
        for (int c = 0; c < VF; ++c) res[c] = fmaxf(res[c], 0.f);
        *(vf_t*)(out + (size_t)v * HFo + f0) = res;
    }
}

// ---------------- pooling (batch_index sorted -> run-length pre-agg) ----------------
__global__ void pool_k(const float* __restrict__ h, const int* __restrict__ batch,
                       float* __restrict__ gsum, float* __restrict__ gmax) {
    int f = threadIdx.x;  // 256
    int n0 = blockIdx.x * 32;
    int nend = min(n0 + 32, N_NODES);
    int cur = -1;
    float sa = 0.f, ma = 0.f;
    for (int n = n0; n < nend; ++n) {
        int g = batch[n];
        float val = h[(size_t)n * 256 + f];
        if (g != cur) {
            if (cur >= 0) {
                atomicAdd(&gsum[cur * 256 + f], sa);
                atomicMax((int*)&gmax[cur * 256 + f], __float_as_int(ma));  // vals >= 0
            }
            cur = g; sa = 0.f; ma = 0.f;
        }
        sa += val;
        ma = fmaxf(ma, val);
    }
    if (cur >= 0) {
        atomicAdd(&gsum[cur * 256 + f], sa);
        atomicMax((int*)&gmax[cur * 256 + f], __float_as_int(ma));
    }
}

__global__ void cnt_k(const int* __restrict__ batch, int* __restrict__ gcnt) {
    int n = blockIdx.x * blockDim.x + threadIdx.x;
    if (n < N_NODES) atomicAdd(&gcnt[batch[n]], 1);
}

__global__ void readout_k(const float* __restrict__ gsum, const float* __restrict__ gmax,
                          const int* __restrict__ gcnt, const float* __restrict__ Wout,
                          const float* __restrict__ bout, float* __restrict__ out) {
    int g = blockIdx.x, lane = threadIdx.x;  // 128 blocks x 64 threads
    float inv = 1.f / fmaxf((float)gcnt[g], 1.f);
    float acc[10];
    #pragma unroll
    for (int j = 0; j < 10; ++j) acc[j] = 0.f;
    for (int f = lane; f < 512; f += 64) {
        float p = (f < 256) ? gsum[g * 256 + f] * inv : gmax[g * 256 + (f - 256)];
        #pragma unroll
        for (int j = 0; j < 10; ++j) acc[j] += p * Wout[f * 10 + j];
    }
    #pragma unroll
    for (int j = 0; j < 10; ++j) {
        float a = acc[j];
        #pragma unroll
        for (int off = 32; off; off >>= 1) a += __shfl_xor(a, off);
        if (lane == 0) out[g * 10 + j] = a + bout[j];
    }
}

extern "C" void kernel_launch(void* const* d_in, const int* in_sizes, int n_in,
                              void* d_out, int out_size, void* d_ws, size_t ws_size,
                              hipStream_t stream) {
    const float* x    = (const float*)d_in[0];
    const int*   ei   = (const int*)d_in[1];
    const int*   batch= (const int*)d_in[2];
    const float* W0   = (const float*)d_in[3];
    const float* as0  = (const float*)d_in[4];
    const float* ad0  = (const float*)d_in[5];
    const float* b0   = (const float*)d_in[6];
    const float* W1   = (const float*)d_in[7];
    const float* as1  = (const float*)d_in[8];
    const float* ad1  = (const float*)d_in[9];
    const float* b1   = (const float*)d_in[10];
    const float* W2   = (const float*)d_in[11];
    const float* as2  = (const float*)d_in[12];
    const float* ad2  = (const float*)d_in[13];
    const float* b2   = (const float*)d_in[14];
    const float* Wout = (const float*)d_in[15];
    const float* bout = (const float*)d_in[16];
    float* out = (float*)d_out;

    char* ws = (char*)d_ws;
    size_t o = 0;
    auto take = [&](size_t bytes) { size_t r = o; o += (bytes + 255) & ~(size_t)255; return r; };
    size_t cnt_o  = take((size_t)N_NODES * 4);
    size_t gsum_o = take((size_t)NG * 256 * 4);
    size_t gmax_o = take((size_t)NG * 256 * 4);
    size_t gcnt_o = take((size_t)NG * 4);
    size_t zero_bytes = o;                       // everything above needs zero-init
    size_t rp_o   = take((size_t)(N_NODES + 1) * 4);
    size_t cur_o  = take((size_t)N_NODES * 4);
    size_t col_o  = take((size_t)E_TOT * 4);
    size_t ssrc_o = take((size_t)N_NODES * NH * 4);
    size_t sdst_o = take((size_t)N_NODES * NH * 4);
    size_t bufA_o = take((size_t)N_NODES * 256 * 4);
    size_t bufB_o = take((size_t)N_NODES * 256 * 4);

    int*   cnt    = (int*)(ws + cnt_o);
    float* gsum   = (float*)(ws + gsum_o);
    float* gmax   = (float*)(ws + gmax_o);
    int*   gcnt   = (int*)(ws + gcnt_o);
    int*   row_ptr= (int*)(ws + rp_o);
    int*   cursor = (int*)(ws + cur_o);
    int*   col    = (int*)(ws + col_o);
    float* ssrc   = (float*)(ws + ssrc_o);
    float* sdst   = (float*)(ws + sdst_o);
    float* bufA   = (float*)(ws + bufA_o);
    float* bufB   = (float*)(ws + bufB_o);

    hipMemsetAsync(ws, 0, zero_bytes, stream);

    count_dst_k<<<(E_TOT + 255) / 256, 256, 0, stream>>>(ei, cnt);
    scan_k<<<1, 1024, 0, stream>>>(cnt, row_ptr, cursor);
    fill_k<<<(E_TOT + 255) / 256, 256, 0, stream>>>(ei, cursor, col);

    int gemm_grid = (N_NODES + 31) / 32;
    int agg_grid  = (N_NODES + 3) / 4;

    // layer 0: 128 -> H4*Fo32 (128)
    gemm_k<128, 128><<<gemm_grid, 256, 0, stream>>>(x, W0, as0, ad0, bufA, ssrc, sdst);
    agg_k<32><<<agg_grid, 256, 0, stream>>>(bufA, ssrc, sdst, row_ptr, col, b0, bufB);

    // layer 1: 128 -> H4*Fo64 (256)
    gemm_k<128, 256><<<gemm_grid, 256, 0, stream>>>(bufB, W1, as1, ad1, bufA, ssrc, sdst);
    agg_k<64><<<agg_grid, 256, 0, stream>>>(bufA, ssrc, sdst, row_ptr, col, b1, bufB);

    // layer 2: 256 -> H4*Fo64 (256)
    gemm_k<256, 256><<<gemm_grid, 256, 0, stream>>>(bufB, W2, as2, ad2, bufA, ssrc, sdst);
    agg_k<64><<<agg_grid, 256, 0, stream>>>(bufA, ssrc, sdst, row_ptr, col, b2, bufB);

    // pooling + readout
    pool_k<<<(N_NODES + 31) / 32, 256, 0, stream>>>(bufB, batch, gsum, gmax);
    cnt_k<<<(N_NODES + 255) / 256, 256, 0, stream>>>(batch, gcnt);
    readout_k<<<NG, 64, 0, stream>>>(gsum, gmax, gcnt, Wout, bout, out);
}

// Round 4
// 871.520 us; speedup vs baseline: 1.3444x; 1.0083x over previous
//
#include <hip/hip_runtime.h>
#include <cfloat>

#define N_NODES 50000
#define N_EDGES 800000
#define E_TOT   850000
#define NG      128
#define NH      4
#define CAP     96   // fast-path max in-degree (Poisson(16)+self-loop; max ~50)

// ---------------- CSR build (by destination) ----------------
__global__ void count_dst_k(const int* __restrict__ ei, int* __restrict__ cnt) {
    int e = blockIdx.x * blockDim.x + threadIdx.x;
    if (e >= E_TOT) return;
    int d = (e < N_EDGES) ? ei[N_EDGES + e] : (e - N_EDGES);
    atomicAdd(&cnt[d], 1);
}

__global__ void scan_k(const int* __restrict__ cnt, int* __restrict__ row_ptr,
                       int* __restrict__ cursor) {
    __shared__ int wsum[16];
    __shared__ int carry_sh;
    int lane = threadIdx.x & 63, wv = threadIdx.x >> 6;
    if (threadIdx.x == 0) carry_sh = 0;
    __syncthreads();
    for (int base = 0; base < N_NODES; base += 1024) {
        int i = base + threadIdx.x;
        int v = (i < N_NODES) ? cnt[i] : 0;
        int s = v;
        #pragma unroll
        for (int off = 1; off < 64; off <<= 1) {
            int t = __shfl_up(s, off);
            if (lane >= off) s += t;
        }
        if (lane == 63) wsum[wv] = s;
        __syncthreads();
        if (wv == 0 && lane < 16) {
            int ws = wsum[lane];
            #pragma unroll
            for (int off = 1; off < 16; off <<= 1) {
                int t = __shfl_up(ws, off);
                if (lane >= off) ws += t;
            }
            wsum[lane] = ws;
        }
        __syncthreads();
        int carry = carry_sh;
        int woff = wv ? wsum[wv - 1] : 0;
        if (i < N_NODES) {
            int rp = carry + woff + s - v;
            row_ptr[i] = rp; cursor[i] = rp;
        }
        __syncthreads();
        if (threadIdx.x == 0) carry_sh = carry + wsum[15];
        __syncthreads();
    }
    if (threadIdx.x == 0) row_ptr[N_NODES] = carry_sh;
}

__global__ void fill_k(const int* __restrict__ ei, int* __restrict__ cursor,
                       int* __restrict__ col) {
    int e = blockIdx.x * blockDim.x + threadIdx.x;
    if (e >= E_TOT) return;
    int s, d;
    if (e < N_EDGES) { s = ei[e]; d = ei[N_EDGES + e]; }
    else { s = e - N_EDGES; d = s; }
    int slot = atomicAdd(&cursor[d], 1);
    col[slot] = s;
}

// ---------------- GEMM + fused attention scores ----------------
template<int K, int NOUT>
__global__ __launch_bounds__(256) void gemm_k(const float* __restrict__ x,
                                              const float* __restrict__ W,
                                              const float* __restrict__ asrc,
                                              const float* __restrict__ adst,
                                              float* __restrict__ out,
                                              float* __restrict__ ssrc,
                                              float* __restrict__ sdst) {
    constexpr int VC = NOUT / 64;  // cols per lane (2 or 4)
    __shared__ float xs[32 * K];
    int row0 = blockIdx.x * 32;
    for (int idx = threadIdx.x; idx < 32 * K / 4; idx += 256) {
        int r = (idx * 4) / K, c = (idx * 4) % K;
        float4 v = make_float4(0.f, 0.f, 0.f, 0.f);
        if (row0 + r < N_NODES) v = *(const float4*)(x + (size_t)(row0 + r) * K + c);
        *(float4*)(xs + r * K + c) = v;
    }
    __syncthreads();
    int wave = threadIdx.x >> 6, lane = threadIdx.x & 63;
    int r0 = wave * 8;
    float acc[8][VC];
    #pragma unroll
    for (int r = 0; r < 8; ++r)
        #pragma unroll
        for (int c = 0; c < VC; ++c) acc[r][c] = 0.f;
    int colb = lane * VC;
    for (int k = 0; k < K; k += 4) {
        float4 xr[8];
        #pragma unroll
        for (int r = 0; r < 8; ++r) xr[r] = *(const float4*)(xs + (r0 + r) * K + k);
        #pragma unroll
        for (int kk = 0; kk < 4; ++kk) {
            float wv[VC];
            if constexpr (VC == 4) {
                float4 t = *(const float4*)(W + (size_t)(k + kk) * NOUT + colb);
                wv[0] = t.x; wv[1] = t.y; wv[2] = t.z; wv[3] = t.w;
            } else {
                float2 t = *(const float2*)(W + (size_t)(k + kk) * NOUT + colb);
                wv[0] = t.x; wv[1] = t.y;
            }
            #pragma unroll
            for (int r = 0; r < 8; ++r) {
                float xv = (kk == 0) ? xr[r].x : (kk == 1) ? xr[r].y
                         : (kk == 2) ? xr[r].z : xr[r].w;
                #pragma unroll
                for (int c = 0; c < VC; ++c) acc[r][c] += xv * wv[c];
            }
        }
    }
    float avs[VC], avd[VC];
    #pragma unroll
    for (int c = 0; c < VC; ++c) { avs[c] = asrc[colb + c]; avd[c] = adst[colb + c]; }
    int hd = lane >> 4, lg = lane & 15;
    #pragma unroll
    for (int r = 0; r < 8; ++r) {
        int row = row0 + r0 + r;
        if (row < N_NODES) {
            if constexpr (VC == 4) {
                *(float4*)(out + (size_t)row * NOUT + colb) =
                    make_float4(acc[r][0], acc[r][1], acc[r][2], acc[r][3]);
            } else {
                *(float2*)(out + (size_t)row * NOUT + colb) =
                    make_float2(acc[r][0], acc[r][1]);
            }
            float ps = 0.f, pd = 0.f;
            #pragma unroll
            for (int c = 0; c < VC; ++c) { ps += acc[r][c] * avs[c]; pd += acc[r][c] * avd[c]; }
            #pragma unroll
            for (int off = 1; off < 16; off <<= 1) {
                ps += __shfl_xor(ps, off);
                pd += __shfl_xor(pd, off);
            }
            if (lg == 0) {
                ssrc[row * NH + hd] = ps;
                sdst[row * NH + hd] = pd;
            }
        }
    }
}

// ---------------- layer-0 aggregation (Fo=32): one wave per node ----------------
template<int Fo>
__global__ __launch_bounds__(256) void agg_k(const float* __restrict__ h,
                                             const float* __restrict__ ssrc,
                                             const float* __restrict__ sdst,
                                             const int* __restrict__ row_ptr,
                                             const int* __restrict__ col,
                                             const float* __restrict__ bias,
                                             float* __restrict__ out) {
    constexpr int HFo = NH * Fo;
    constexpr int VF = Fo / 16;
    typedef float vf_t __attribute__((ext_vector_type(VF)));
    __shared__ int   colL[4][CAP];
    __shared__ float aw[4][NH][CAP + 1];
    int wv = threadIdx.x >> 6, lane = threadIdx.x & 63;
    int v = blockIdx.x * 4 + wv;
    if (v >= N_NODES) return;
    int hd = lane >> 4, lg = lane & 15;
    int beg = row_ptr[v], cnt = row_ptr[v + 1] - beg;
    float sdv = sdst[v * NH + hd];
    int f0 = lane * VF;

    if (cnt <= CAP) {
        for (int j = lane; j < cnt; j += 64) colL[wv][j] = col[beg + j];
        __builtin_amdgcn_wave_barrier();
        float m = -FLT_MAX;
        for (int j = lg; j < cnt; j += 16) {
            int u = colL[wv][j];
            float e = ssrc[u * NH + hd] + sdv;
            e = (e > 0.f) ? e : 0.2f * e;
            aw[wv][hd][j] = e;
            m = fmaxf(m, e);
        }
        #pragma unroll
        for (int off = 1; off < 16; off <<= 1) m = fmaxf(m, __shfl_xor(m, off));
        __builtin_amdgcn_wave_barrier();
        float den = 0.f;
        for (int j = lg; j < cnt; j += 16) {
            float wj = __expf(aw[wv][hd][j] - m);
            aw[wv][hd][j] = wj;
            den += wj;
        }
        #pragma unroll
        for (int off = 1; off < 16; off <<= 1) den += __shfl_xor(den, off);
        float inv = 1.f / (den + 1e-16f);
        __builtin_amdgcn_wave_barrier();
        vf_t acc = {};
        int j = 0;
        for (; j + 4 <= cnt; j += 4) {
            int u0 = colL[wv][j],     u1 = colL[wv][j + 1];
            int u2 = colL[wv][j + 2], u3 = colL[wv][j + 3];
            float w0 = aw[wv][hd][j],     w1 = aw[wv][hd][j + 1];
            float w2 = aw[wv][hd][j + 2], w3 = aw[wv][hd][j + 3];
            vf_t h0 = *(const vf_t*)(h + (size_t)u0 * HFo + f0);
            vf_t h1 = *(const vf_t*)(h + (size_t)u1 * HFo + f0);
            vf_t h2 = *(const vf_t*)(h + (size_t)u2 * HFo + f0);
            vf_t h3 = *(const vf_t*)(h + (size_t)u3 * HFo + f0);
            acc += w0 * h0;
            acc += w1 * h1;
            acc += w2 * h2;
            acc += w3 * h3;
        }
        for (; j < cnt; ++j) {
            int u = colL[wv][j];
            float wj = aw[wv][hd][j];
            vf_t hv = *(const vf_t*)(h + (size_t)u * HFo + f0);
            acc += wj * hv;
        }
        vf_t bv = *(const vf_t*)(bias + f0);
        vf_t res = acc * inv + bv;
        #pragma unroll
        for (int c = 0; c < VF; ++c) res[c] = fmaxf(res[c], 0.f);
        __builtin_nontemporal_store(res, (vf_t*)(out + (size_t)v * HFo + f0));
    } else {
        float m = -FLT_MAX;
        for (int j = lg; j < cnt; j += 16) {
            int u = col[beg + j];
            float e = ssrc[u * NH + hd] + sdv;
            e = (e > 0.f) ? e : 0.2f * e;
            m = fmaxf(m, e);
        }
        #pragma unroll
        for (int off = 1; off < 16; off <<= 1) m = fmaxf(m, __shfl_xor(m, off));
        float den = 0.f;
        vf_t acc = {};
        for (int j = 0; j < cnt; ++j) {
            int u = col[beg + j];
            float e = ssrc[u * NH + hd] + sdv;
            e = (e > 0.f) ? e : 0.2f * e;
            float wj = __expf(e - m);
            den += wj;
            vf_t hv = *(const vf_t*)(h + (size_t)u * HFo + f0);
            acc += wj * hv;
        }
        float inv = 1.f / (den + 1e-16f);
        vf_t bv = *(const vf_t*)(bias + f0);
        vf_t res = acc * inv + bv;
        #pragma unroll
        for (int c = 0; c < VF; ++c) res[c] = fmaxf(res[c], 0.f);
        *(vf_t*)(out + (size_t)v * HFo + f0) = res;
    }
}

// ---------------- Fo=64 aggregation: feature-split 2-pass ----------------
// PASS p covers features [p*128, p*128+128) = heads {2p, 2p+1}; 512 B row
// gathers (float2/lane) so each pass's working set is 25.6 MB (~L2-sized).
// One wave per node; 32-lane head groups; softmax recomputed per pass.
template<int PASS>
__global__ __launch_bounds__(256) void agg64_k(const float* __restrict__ h,
                                               const float* __restrict__ ssrc,
                                               const float* __restrict__ sdst,
                                               const int* __restrict__ row_ptr,
                                               const int* __restrict__ col,
                                               const float* __restrict__ bias,
                                               float* __restrict__ out) {
    typedef float f2 __attribute__((ext_vector_type(2)));
    __shared__ int   colL[4][CAP];
    __shared__ float aw[4][2][CAP + 1];
    int wv = threadIdx.x >> 6, lane = threadIdx.x & 63;
    int v = blockIdx.x * 4 + wv;
    if (v >= N_NODES) return;
    int hl = lane >> 5, hd = PASS * 2 + hl, lg = lane & 31;
    int beg = row_ptr[v], cnt = row_ptr[v + 1] - beg;
    float sdv = sdst[v * NH + hd];
    int f0 = PASS * 128 + lane * 2;   // global feature index; f0/64 == hd

    if (cnt <= CAP) {
        for (int j = lane; j < cnt; j += 64) colL[wv][j] = col[beg + j];
        __builtin_amdgcn_wave_barrier();
        float m = -FLT_MAX;
        for (int j = lg; j < cnt; j += 32) {
            int u = colL[wv][j];
            float e = ssrc[u * NH + hd] + sdv;
            e = (e > 0.f) ? e : 0.2f * e;
            aw[wv][hl][j] = e;
            m = fmaxf(m, e);
        }
        #pragma unroll
        for (int off = 1; off < 32; off <<= 1) m = fmaxf(m, __shfl_xor(m, off));
        __builtin_amdgcn_wave_barrier();
        float den = 0.f;
        for (int j = lg; j < cnt; j += 32) {
            float wj = __expf(aw[wv][hl][j] - m);
            aw[wv][hl][j] = wj;
            den += wj;
        }
        #pragma unroll
        for (int off = 1; off < 32; off <<= 1) den += __shfl_xor(den, off);
        float inv = 1.f / (den + 1e-16f);
        __builtin_amdgcn_wave_barrier();
        f2 acc = {};
        int j = 0;
        for (; j + 8 <= cnt; j += 8) {
            int u[8]; float w[8]; f2 hv[8];
            #pragma unroll
            for (int i = 0; i < 8; ++i) { u[i] = colL[wv][j + i]; w[i] = aw[wv][hl][j + i]; }
            #pragma unroll
            for (int i = 0; i < 8; ++i) hv[i] = *(const f2*)(h + (size_t)u[i] * 256 + f0);
            #pragma unroll
            for (int i = 0; i < 8; ++i) acc += w[i] * hv[i];
        }
        for (; j < cnt; ++j) {
            int u = colL[wv][j];
            float wj = aw[wv][hl][j];
            f2 hv = *(const f2*)(h + (size_t)u * 256 + f0);
            acc += wj * hv;
        }
        f2 bv = *(const f2*)(bias + f0);
        f2 res = acc * inv + bv;
        res[0] = fmaxf(res[0], 0.f);
        res[1] = fmaxf(res[1], 0.f);
        __builtin_nontemporal_store(res, (f2*)(out + (size_t)v * 256 + f0));
    } else {
        float m = -FLT_MAX;
        for (int j = lg; j < cnt; j += 32) {
            int u = col[beg + j];
            float e = ssrc[u * NH + hd] + sdv;
            e = (e > 0.f) ? e : 0.2f * e;
            m = fmaxf(m, e);
        }
        #pragma unroll
        for (int off = 1; off < 32; off <<= 1) m = fmaxf(m, __shfl_xor(m, off));
        float den = 0.f;
        f2 acc = {};
        for (int j = 0; j < cnt; ++j) {
            int u = col[beg + j];
            float e = ssrc[u * NH + hd] + sdv;
            e = (e > 0.f) ? e : 0.2f * e;
            float wj = __expf(e - m);
            den += wj;
            f2 hv = *(const f2*)(h + (size_t)u * 256 + f0);
            acc += wj * hv;
        }
        float inv = 1.f / (den + 1e-16f);
        f2 bv = *(const f2*)(bias + f0);
        f2 res = acc * inv + bv;
        res[0] = fmaxf(res[0], 0.f);
        res[1] = fmaxf(res[1], 0.f);
        *(f2*)(out + (size_t)v * 256 + f0) = res;
    }
}

// ---------------- pooling (batch_index sorted -> run-length pre-agg) ----------------
__global__ void pool_k(const float* __restrict__ h, const int* __restrict__ batch,
                       float* __restrict__ gsum, float* __restrict__ gmax) {
    int f = threadIdx.x;  // 256
    int n0 = blockIdx.x * 32;
    int nend = min(n0 + 32, N_NODES);
    int cur = -1;
    float sa = 0.f, ma = 0.f;
    for (int n = n0; n < nend; ++n) {
        int g = batch[n];
        float val = h[(size_t)n * 256 + f];
        if (g != cur) {
            if (cur >= 0) {
                atomicAdd(&gsum[cur * 256 + f], sa);
                atomicMax((int*)&gmax[cur * 256 + f], __float_as_int(ma));
            }
            cur = g; sa = 0.f; ma = 0.f;
        }
        sa += val;
        ma = fmaxf(ma, val);
    }
    if (cur >= 0) {
        atomicAdd(&gsum[cur * 256 + f], sa);
        atomicMax((int*)&gmax[cur * 256 + f], __float_as_int(ma));
    }
}

__global__ void cnt_k(const int* __restrict__ batch, int* __restrict__ gcnt) {
    int n = blockIdx.x * blockDim.x + threadIdx.x;
    if (n < N_NODES) atomicAdd(&gcnt[batch[n]], 1);
}

__global__ void readout_k(const float* __restrict__ gsum, const float* __restrict__ gmax,
                          const int* __restrict__ gcnt, const float* __restrict__ Wout,
                          const float* __restrict__ bout, float* __restrict__ out) {
    int g = blockIdx.x, lane = threadIdx.x;
    float inv = 1.f / fmaxf((float)gcnt[g], 1.f);
    float acc[10];
    #pragma unroll
    for (int j = 0; j < 10; ++j) acc[j] = 0.f;
    for (int f = lane; f < 512; f += 64) {
        float p = (f < 256) ? gsum[g * 256 + f] * inv : gmax[g * 256 + (f - 256)];
        #pragma unroll
        for (int j = 0; j < 10; ++j) acc[j] += p * Wout[f * 10 + j];
    }
    #pragma unroll
    for (int j = 0; j < 10; ++j) {
        float a = acc[j];
        #pragma unroll
        for (int off = 32; off; off >>= 1) a += __shfl_xor(a, off);
        if (lane == 0) out[g * 10 + j] = a + bout[j];
    }
}

extern "C" void kernel_launch(void* const* d_in, const int* in_sizes, int n_in,
                              void* d_out, int out_size, void* d_ws, size_t ws_size,
                              hipStream_t stream) {
    const float* x    = (const float*)d_in[0];
    const int*   ei   = (const int*)d_in[1];
    const int*   batch= (const int*)d_in[2];
    const float* W0   = (const float*)d_in[3];
    const float* as0  = (const float*)d_in[4];
    const float* ad0  = (const float*)d_in[5];
    const float* b0   = (const float*)d_in[6];
    const float* W1   = (const float*)d_in[7];
    const float* as1  = (const float*)d_in[8];
    const float* ad1  = (const float*)d_in[9];
    const float* b1   = (const float*)d_in[10];
    const float* W2   = (const float*)d_in[11];
    const float* as2  = (const float*)d_in[12];
    const float* ad2  = (const float*)d_in[13];
    const float* b2   = (const float*)d_in[14];
    const float* Wout = (const float*)d_in[15];
    const float* bout = (const float*)d_in[16];
    float* out = (float*)d_out;

    char* ws = (char*)d_ws;
    size_t o = 0;
    auto take = [&](size_t bytes) { size_t r = o; o += (bytes + 255) & ~(size_t)255; return r; };
    size_t cnt_o  = take((size_t)N_NODES * 4);
    size_t gsum_o = take((size_t)NG * 256 * 4);
    size_t gmax_o = take((size_t)NG * 256 * 4);
    size_t gcnt_o = take((size_t)NG * 4);
    size_t zero_bytes = o;
    size_t rp_o   = take((size_t)(N_NODES + 1) * 4);
    size_t cur_o  = take((size_t)N_NODES * 4);
    size_t col_o  = take((size_t)E_TOT * 4);
    size_t ssrc_o = take((size_t)N_NODES * NH * 4);
    size_t sdst_o = take((size_t)N_NODES * NH * 4);
    size_t bufA_o = take((size_t)N_NODES * 256 * 4);
    size_t bufB_o = take((size_t)N_NODES * 256 * 4);

    int*   cnt    = (int*)(ws + cnt_o);
    float* gsum   = (float*)(ws + gsum_o);
    float* gmax   = (float*)(ws + gmax_o);
    int*   gcnt   = (int*)(ws + gcnt_o);
    int*   row_ptr= (int*)(ws + rp_o);
    int*   cursor = (int*)(ws + cur_o);
    int*   col    = (int*)(ws + col_o);
    float* ssrc   = (float*)(ws + ssrc_o);
    float* sdst   = (float*)(ws + sdst_o);
    float* bufA   = (float*)(ws + bufA_o);
    float* bufB   = (float*)(ws + bufB_o);

    hipMemsetAsync(ws, 0, zero_bytes, stream);

    count_dst_k<<<(E_TOT + 255) / 256, 256, 0, stream>>>(ei, cnt);
    scan_k<<<1, 1024, 0, stream>>>(cnt, row_ptr, cursor);
    fill_k<<<(E_TOT + 255) / 256, 256, 0, stream>>>(ei, cursor, col);

    int gemm_grid = (N_NODES + 31) / 32;
    int agg_grid  = (N_NODES + 3) / 4;

    // layer 0: 128 -> H4*Fo32 (128)
    gemm_k<128, 128><<<gemm_grid, 256, 0, stream>>>(x, W0, as0, ad0, bufA, ssrc, sdst);
    agg_k<32><<<agg_grid, 256, 0, stream>>>(bufA, ssrc, sdst, row_ptr, col, b0, bufB);

    // layer 1: 128 -> H4*Fo64 (256), aggregation feature-split into 2 passes
    gemm_k<128, 256><<<gemm_grid, 256, 0, stream>>>(bufB, W1, as1, ad1, bufA, ssrc, sdst);
    agg64_k<0><<<agg_grid, 256, 0, stream>>>(bufA, ssrc, sdst, row_ptr, col, b1, bufB);
    agg64_k<1><<<agg_grid, 256, 0, stream>>>(bufA, ssrc, sdst, row_ptr, col, b1, bufB);

    // layer 2: 256 -> H4*Fo64 (256), same split
    gemm_k<256, 256><<<gemm_grid, 256, 0, stream>>>(bufB, W2, as2, ad2, bufA, ssrc, sdst);
    agg64_k<0><<<agg_grid, 256, 0, stream>>>(bufA, ssrc, sdst, row_ptr, col, b2, bufB);
    agg64_k<1><<<agg_grid, 256, 0, stream>>>(bufA, ssrc, sdst, row_ptr, col, b2, bufB);

    // pooling + readout
    pool_k<<<(N_NODES + 31) / 32, 256, 0, stream>>>(bufB, batch, gsum, gmax);
    cnt_k<<<(N_NODES + 255) / 256, 256, 0, stream>>>(batch, gcnt);
    readout_k<<<NG, 64, 0, stream>>>(gsum, gmax, gcnt, Wout, bout, out);
}

// Round 5
// 856.604 us; speedup vs baseline: 1.3678x; 1.0174x over previous
//
#include <hip/hip_runtime.h>
#include <cfloat>

#define N_NODES 50000
#define N_EDGES 800000
#define E_TOT   850000
#define NG      128
#define NH      4
#define CAP     96   // fast-path max in-degree (Poisson(16)+self-loop; max ~45)

// ---------------- CSR build (by destination) ----------------
__global__ void count_dst_k(const int* __restrict__ ei, int* __restrict__ cnt) {
    int e = blockIdx.x * blockDim.x + threadIdx.x;
    if (e >= E_TOT) return;
    int d = (e < N_EDGES) ? ei[N_EDGES + e] : (e - N_EDGES);
    atomicAdd(&cnt[d], 1);
}

__global__ void scan_k(const int* __restrict__ cnt, int* __restrict__ row_ptr,
                       int* __restrict__ cursor) {
    __shared__ int wsum[16];
    __shared__ int carry_sh;
    int lane = threadIdx.x & 63, wv = threadIdx.x >> 6;
    if (threadIdx.x == 0) carry_sh = 0;
    __syncthreads();
    for (int base = 0; base < N_NODES; base += 1024) {
        int i = base + threadIdx.x;
        int v = (i < N_NODES) ? cnt[i] : 0;
        int s = v;
        #pragma unroll
        for (int off = 1; off < 64; off <<= 1) {
            int t = __shfl_up(s, off);
            if (lane >= off) s += t;
        }
        if (lane == 63) wsum[wv] = s;
        __syncthreads();
        if (wv == 0 && lane < 16) {
            int ws = wsum[lane];
            #pragma unroll
            for (int off = 1; off < 16; off <<= 1) {
                int t = __shfl_up(ws, off);
                if (lane >= off) ws += t;
            }
            wsum[lane] = ws;
        }
        __syncthreads();
        int carry = carry_sh;
        int woff = wv ? wsum[wv - 1] : 0;
        if (i < N_NODES) {
            int rp = carry + woff + s - v;
            row_ptr[i] = rp; cursor[i] = rp;
        }
        __syncthreads();
        if (threadIdx.x == 0) carry_sh = carry + wsum[15];
        __syncthreads();
    }
    if (threadIdx.x == 0) row_ptr[N_NODES] = carry_sh;
}

__global__ void fill_k(const int* __restrict__ ei, int* __restrict__ cursor,
                       int* __restrict__ col) {
    int e = blockIdx.x * blockDim.x + threadIdx.x;
    if (e >= E_TOT) return;
    int s, d;
    if (e < N_EDGES) { s = ei[e]; d = ei[N_EDGES + e]; }
    else { s = e - N_EDGES; d = s; }
    int slot = atomicAdd(&cursor[d], 1);
    col[slot] = s;
}

// ---------------- GEMM + fused attention scores ----------------
template<int K, int NOUT>
__global__ __launch_bounds__(256) void gemm_k(const float* __restrict__ x,
                                              const float* __restrict__ W,
                                              const float* __restrict__ asrc,
                                              const float* __restrict__ adst,
                                              float* __restrict__ out,
                                              float* __restrict__ ssrc,
                                              float* __restrict__ sdst) {
    constexpr int VC = NOUT / 64;  // cols per lane (2 or 4)
    __shared__ float xs[32 * K];
    int row0 = blockIdx.x * 32;
    for (int idx = threadIdx.x; idx < 32 * K / 4; idx += 256) {
        int r = (idx * 4) / K, c = (idx * 4) % K;
        float4 v = make_float4(0.f, 0.f, 0.f, 0.f);
        if (row0 + r < N_NODES) v = *(const float4*)(x + (size_t)(row0 + r) * K + c);
        *(float4*)(xs + r * K + c) = v;
    }
    __syncthreads();
    int wave = threadIdx.x >> 6, lane = threadIdx.x & 63;
    int r0 = wave * 8;
    float acc[8][VC];
    #pragma unroll
    for (int r = 0; r < 8; ++r)
        #pragma unroll
        for (int c = 0; c < VC; ++c) acc[r][c] = 0.f;
    int colb = lane * VC;
    for (int k = 0; k < K; k += 4) {
        float4 xr[8];
        #pragma unroll
        for (int r = 0; r < 8; ++r) xr[r] = *(const float4*)(xs + (r0 + r) * K + k);
        #pragma unroll
        for (int kk = 0; kk < 4; ++kk) {
            float wv[VC];
            if constexpr (VC == 4) {
                float4 t = *(const float4*)(W + (size_t)(k + kk) * NOUT + colb);
                wv[0] = t.x; wv[1] = t.y; wv[2] = t.z; wv[3] = t.w;
            } else {
                float2 t = *(const float2*)(W + (size_t)(k + kk) * NOUT + colb);
                wv[0] = t.x; wv[1] = t.y;
            }
            #pragma unroll
            for (int r = 0; r < 8; ++r) {
                float xv = (kk == 0) ? xr[r].x : (kk == 1) ? xr[r].y
                         : (kk == 2) ? xr[r].z : xr[r].w;
                #pragma unroll
                for (int c = 0; c < VC; ++c) acc[r][c] += xv * wv[c];
            }
        }
    }
    float avs[VC], avd[VC];
    #pragma unroll
    for (int c = 0; c < VC; ++c) { avs[c] = asrc[colb + c]; avd[c] = adst[colb + c]; }
    int hd = lane >> 4, lg = lane & 15;
    #pragma unroll
    for (int r = 0; r < 8; ++r) {
        int row = row0 + r0 + r;
        if (row < N_NODES) {
            if constexpr (VC == 4) {
                *(float4*)(out + (size_t)row * NOUT + colb) =
                    make_float4(acc[r][0], acc[r][1], acc[r][2], acc[r][3]);
            } else {
                *(float2*)(out + (size_t)row * NOUT + colb) =
                    make_float2(acc[r][0], acc[r][1]);
            }
            float ps = 0.f, pd = 0.f;
            #pragma unroll
            for (int c = 0; c < VC; ++c) { ps += acc[r][c] * avs[c]; pd += acc[r][c] * avd[c]; }
            #pragma unroll
            for (int off = 1; off < 16; off <<= 1) {
                ps += __shfl_xor(ps, off);
                pd += __shfl_xor(pd, off);
            }
            if (lg == 0) {
                ssrc[row * NH + hd] = ps;
                sdst[row * NH + hd] = pd;
            }
        }
    }
}

// ---------------- XCD-sharded aggregation ----------------
// slice s = blockIdx % 8 -> lands on XCD s (round-robin dispatch heuristic);
// all gathers of feature slice s concentrate on one XCD's L2.
// SF lanes per node (SF = HFo/8); 64/SF nodes per wave; scalar 4B gathers.
template<int HFo, int SF>
__global__ __launch_bounds__(256) void agg_slice_k(const float* __restrict__ h,
                                                   const float* __restrict__ ssrc,
                                                   const float* __restrict__ sdst,
                                                   const int* __restrict__ row_ptr,
                                                   const int* __restrict__ col,
                                                   const float* __restrict__ bias,
                                                   float* __restrict__ out) {
    constexpr int Fo  = HFo / NH;
    constexpr int NPW = 64 / SF;   // nodes per wave
    constexpr int NPB = 4 * NPW;   // nodes per block
    __shared__ int   colL[NPB][CAP];
    __shared__ float aw[NPB][CAP];
    int s = blockIdx.x & 7;
    int g = blockIdx.x >> 3;
    int wv = threadIdx.x >> 6, lane = threadIdx.x & 63;
    int sub = lane / SF, lg = lane % SF;
    int nb = wv * NPW + sub;
    int v = g * NPB + nb;
    if (v >= N_NODES) return;
    int f0 = s * SF + lg;
    int hd = f0 / Fo;              // uniform per block (SF <= Fo/... : s*SF..s*SF+SF-1 same head)
    int beg = row_ptr[v], cnt = row_ptr[v + 1] - beg;
    float sdv = sdst[v * NH + hd];

    if (cnt <= CAP) {
        for (int j = lg; j < cnt; j += SF) colL[nb][j] = col[beg + j];
        __builtin_amdgcn_wave_barrier();
        // pre-activation scores + exact max (strided over SF-lane group)
        float m = -FLT_MAX;
        for (int j = lg; j < cnt; j += SF) {
            int u = colL[nb][j];
            float e = ssrc[u * NH + hd] + sdv;
            e = (e > 0.f) ? e : 0.2f * e;
            aw[nb][j] = e;
            m = fmaxf(m, e);
        }
        #pragma unroll
        for (int off = SF >> 1; off; off >>= 1) m = fmaxf(m, __shfl_xor(m, off));
        __builtin_amdgcn_wave_barrier();
        float den = 0.f;
        for (int j = lg; j < cnt; j += SF) {
            float wj = __expf(aw[nb][j] - m);
            aw[nb][j] = wj;
            den += wj;
        }
        #pragma unroll
        for (int off = SF >> 1; off; off >>= 1) den += __shfl_xor(den, off);
        float inv = 1.f / (den + 1e-16f);
        __builtin_amdgcn_wave_barrier();
        // gather: scalar 4B per lane, SF*4 B coalesced per node-group, unroll 8
        float acc = 0.f;
        int j = 0;
        for (; j + 8 <= cnt; j += 8) {
            int u[8]; float w[8], hv[8];
            #pragma unroll
            for (int i = 0; i < 8; ++i) { u[i] = colL[nb][j + i]; w[i] = aw[nb][j + i]; }
            #pragma unroll
            for (int i = 0; i < 8; ++i) hv[i] = h[(size_t)u[i] * HFo + f0];
            #pragma unroll
            for (int i = 0; i < 8; ++i) acc += w[i] * hv[i];
        }
        for (; j < cnt; ++j)
            acc += aw[nb][j] * h[(size_t)colL[nb][j] * HFo + f0];
        float res = fmaxf(acc * inv + bias[f0], 0.f);
        __builtin_nontemporal_store(res, out + (size_t)v * HFo + f0);
    } else {
        // slow path (practically never): streaming, exact
        float m = -FLT_MAX;
        for (int j = lg; j < cnt; j += SF) {
            int u = col[beg + j];
            float e = ssrc[u * NH + hd] + sdv;
            e = (e > 0.f) ? e : 0.2f * e;
            m = fmaxf(m, e);
        }
        #pragma unroll
        for (int off = SF >> 1; off; off >>= 1) m = fmaxf(m, __shfl_xor(m, off));
        float den = 0.f, acc = 0.f;
        for (int j = 0; j < cnt; ++j) {
            int u = col[beg + j];
            float e = ssrc[u * NH + hd] + sdv;
            e = (e > 0.f) ? e : 0.2f * e;
            float wj = __expf(e - m);
            den += wj;
            acc += wj * h[(size_t)u * HFo + f0];
        }
        float inv = 1.f / (den + 1e-16f);
        out[(size_t)v * HFo + f0] = fmaxf(acc * inv + bias[f0], 0.f);
    }
}

// ---------------- pooling (batch_index sorted -> run-length pre-agg) ----------------
__global__ void pool_k(const float* __restrict__ h, const int* __restrict__ batch,
                       float* __restrict__ gsum, float* __restrict__ gmax) {
    int f = threadIdx.x;  // 256
    int n0 = blockIdx.x * 32;
    int nend = min(n0 + 32, N_NODES);
    int cur = -1;
    float sa = 0.f, ma = 0.f;
    for (int n = n0; n < nend; ++n) {
        int g = batch[n];
        float val = h[(size_t)n * 256 + f];
        if (g != cur) {
            if (cur >= 0) {
                atomicAdd(&gsum[cur * 256 + f], sa);
                atomicMax((int*)&gmax[cur * 256 + f], __float_as_int(ma));
            }
            cur = g; sa = 0.f; ma = 0.f;
        }
        sa += val;
        ma = fmaxf(ma, val);
    }
    if (cur >= 0) {
        atomicAdd(&gsum[cur * 256 + f], sa);
        atomicMax((int*)&gmax[cur * 256 + f], __float_as_int(ma));
    }
}

// batch sorted -> per-graph count = boundary difference (binary search, 1 block)
__global__ void gcnt_k(const int* __restrict__ batch, int* __restrict__ gcnt) {
    int g = threadIdx.x;  // 128 threads
    if (g >= NG) return;
    int lo = 0, hi = N_NODES;
    while (lo < hi) { int mid = (lo + hi) >> 1; if (batch[mid] < g) lo = mid + 1; else hi = mid; }
    int b0 = lo;
    lo = 0; hi = N_NODES;
    while (lo < hi) { int mid = (lo + hi) >> 1; if (batch[mid] < g + 1) lo = mid + 1; else hi = mid; }
    gcnt[g] = lo - b0;
}

__global__ void readout_k(const float* __restrict__ gsum, const float* __restrict__ gmax,
                          const int* __restrict__ gcnt, const float* __restrict__ Wout,
                          const float* __restrict__ bout, float* __restrict__ out) {
    int g = blockIdx.x, lane = threadIdx.x;
    float inv = 1.f / fmaxf((float)gcnt[g], 1.f);
    float acc[10];
    #pragma unroll
    for (int j = 0; j < 10; ++j) acc[j] = 0.f;
    for (int f = lane; f < 512; f += 64) {
        float p = (f < 256) ? gsum[g * 256 + f] * inv : gmax[g * 256 + (f - 256)];
        #pragma unroll
        for (int j = 0; j < 10; ++j) acc[j] += p * Wout[f * 10 + j];
    }
    #pragma unroll
    for (int j = 0; j < 10; ++j) {
        float a = acc[j];
        #pragma unroll
        for (int off = 32; off; off >>= 1) a += __shfl_xor(a, off);
        if (lane == 0) out[g * 10 + j] = a + bout[j];
    }
}

extern "C" void kernel_launch(void* const* d_in, const int* in_sizes, int n_in,
                              void* d_out, int out_size, void* d_ws, size_t ws_size,
                              hipStream_t stream) {
    const float* x    = (const float*)d_in[0];
    const int*   ei   = (const int*)d_in[1];
    const int*   batch= (const int*)d_in[2];
    const float* W0   = (const float*)d_in[3];
    const float* as0  = (const float*)d_in[4];
    const float* ad0  = (const float*)d_in[5];
    const float* b0   = (const float*)d_in[6];
    const float* W1   = (const float*)d_in[7];
    const float* as1  = (const float*)d_in[8];
    const float* ad1  = (const float*)d_in[9];
    const float* b1   = (const float*)d_in[10];
    const float* W2   = (const float*)d_in[11];
    const float* as2  = (const float*)d_in[12];
    const float* ad2  = (const float*)d_in[13];
    const float* b2   = (const float*)d_in[14];
    const float* Wout = (const float*)d_in[15];
    const float* bout = (const float*)d_in[16];
    float* out = (float*)d_out;

    char* ws = (char*)d_ws;
    size_t o = 0;
    auto take = [&](size_t bytes) { size_t r = o; o += (bytes + 255) & ~(size_t)255; return r; };
    size_t cnt_o  = take((size_t)N_NODES * 4);
    size_t gsum_o = take((size_t)NG * 256 * 4);
    size_t gmax_o = take((size_t)NG * 256 * 4);
    size_t gcnt_o = take((size_t)NG * 4);
    size_t zero_bytes = o;
    size_t rp_o   = take((size_t)(N_NODES + 1) * 4);
    size_t cur_o  = take((size_t)N_NODES * 4);
    size_t col_o  = take((size_t)E_TOT * 4);
    size_t ssrc_o = take((size_t)N_NODES * NH * 4);
    size_t sdst_o = take((size_t)N_NODES * NH * 4);
    size_t bufA_o = take((size_t)N_NODES * 256 * 4);
    size_t bufB_o = take((size_t)N_NODES * 256 * 4);

    int*   cnt    = (int*)(ws + cnt_o);
    float* gsum   = (float*)(ws + gsum_o);
    float* gmax   = (float*)(ws + gmax_o);
    int*   gcnt   = (int*)(ws + gcnt_o);
    int*   row_ptr= (int*)(ws + rp_o);
    int*   cursor = (int*)(ws + cur_o);
    int*   col    = (int*)(ws + col_o);
    float* ssrc   = (float*)(ws + ssrc_o);
    float* sdst   = (float*)(ws + sdst_o);
    float* bufA   = (float*)(ws + bufA_o);
    float* bufB   = (float*)(ws + bufB_o);

    hipMemsetAsync(ws, 0, zero_bytes, stream);

    count_dst_k<<<(E_TOT + 255) / 256, 256, 0, stream>>>(ei, cnt);
    scan_k<<<1, 1024, 0, stream>>>(cnt, row_ptr, cursor);
    fill_k<<<(E_TOT + 255) / 256, 256, 0, stream>>>(ei, cursor, col);

    int gemm_grid = (N_NODES + 31) / 32;
    // agg grids: 8 slices x node-groups (NPB = 16 for HFo=128, 8 for HFo=256)
    int agg128_grid = 8 * ((N_NODES + 15) / 16);
    int agg256_grid = 8 * ((N_NODES + 7) / 8);

    // layer 0: 128 -> H4*Fo32 (128)
    gemm_k<128, 128><<<gemm_grid, 256, 0, stream>>>(x, W0, as0, ad0, bufA, ssrc, sdst);
    agg_slice_k<128, 16><<<agg128_grid, 256, 0, stream>>>(bufA, ssrc, sdst, row_ptr, col, b0, bufB);

    // layer 1: 128 -> H4*Fo64 (256)
    gemm_k<128, 256><<<gemm_grid, 256, 0, stream>>>(bufB, W1, as1, ad1, bufA, ssrc, sdst);
    agg_slice_k<256, 32><<<agg256_grid, 256, 0, stream>>>(bufA, ssrc, sdst, row_ptr, col, b1, bufB);

    // layer 2: 256 -> H4*Fo64 (256)
    gemm_k<256, 256><<<gemm_grid, 256, 0, stream>>>(bufB, W2, as2, ad2, bufA, ssrc, sdst);
    agg_slice_k<256, 32><<<agg256_grid, 256, 0, stream>>>(bufA, ssrc, sdst, row_ptr, col, b2, bufB);

    // pooling + readout
    pool_k<<<(N_NODES + 31) / 32, 256, 0, stream>>>(bufB, batch, gsum, gmax);
    gcnt_k<<<1, 128, 0, stream>>>(batch, gcnt);
    readout_k<<<NG, 64, 0, stream>>>(gsum, gmax, gcnt, Wout, bout, out);
}

// Round 7
// 855.715 us; speedup vs baseline: 1.3693x; 1.0010x over previous
//
#include <hip/hip_runtime.h>
#include <cfloat>

#define N_NODES 50000
#define N_EDGES 800000
#define E_TOT   850000
#define NG      128
#define NH      4

typedef float f4 __attribute__((ext_vector_type(4)));

// ---------------- CSR build (by destination) ----------------
__global__ void count_dst_k(const int* __restrict__ ei, int* __restrict__ cnt) {
    int e = blockIdx.x * blockDim.x + threadIdx.x;
    if (e >= E_TOT) return;
    int d = (e < N_EDGES) ? ei[N_EDGES + e] : (e - N_EDGES);
    atomicAdd(&cnt[d], 1);
}

__global__ void scan_k(const int* __restrict__ cnt, int* __restrict__ row_ptr,
                       int* __restrict__ cursor) {
    __shared__ int wsum[16];
    __shared__ int carry_sh;
    int lane = threadIdx.x & 63, wv = threadIdx.x >> 6;
    if (threadIdx.x == 0) carry_sh = 0;
    __syncthreads();
    for (int base = 0; base < N_NODES; base += 1024) {
        int i = base + threadIdx.x;
        int v = (i < N_NODES) ? cnt[i] : 0;
        int s = v;
        #pragma unroll
        for (int off = 1; off < 64; off <<= 1) {
            int t = __shfl_up(s, off);
            if (lane >= off) s += t;
        }
        if (lane == 63) wsum[wv] = s;
        __syncthreads();
        if (wv == 0 && lane < 16) {
            int ws = wsum[lane];
            #pragma unroll
            for (int off = 1; off < 16; off <<= 1) {
                int t = __shfl_up(ws, off);
                if (lane >= off) ws += t;
            }
            wsum[lane] = ws;
        }
        __syncthreads();
        int carry = carry_sh;
        int woff = wv ? wsum[wv - 1] : 0;
        if (i < N_NODES) {
            int rp = carry + woff + s - v;
            row_ptr[i] = rp; cursor[i] = rp;
        }
        __syncthreads();
        if (threadIdx.x == 0) carry_sh = carry + wsum[15];
        __syncthreads();
    }
    if (threadIdx.x == 0) row_ptr[N_NODES] = carry_sh;
}

__global__ void fill_k(const int* __restrict__ ei, int* __restrict__ cursor,
                       int* __restrict__ col) {
    int e = blockIdx.x * blockDim.x + threadIdx.x;
    if (e >= E_TOT) return;
    int s, d;
    if (e < N_EDGES) { s = ei[e]; d = ei[N_EDGES + e]; }
    else { s = e - N_EDGES; d = s; }
    int slot = atomicAdd(&cursor[d], 1);
    col[slot] = s;
}

// ---------------- GEMM + fused attention scores ----------------
template<int K, int NOUT>
__global__ __launch_bounds__(256) void gemm_k(const float* __restrict__ x,
                                              const float* __restrict__ W,
                                              const float* __restrict__ asrc,
                                              const float* __restrict__ adst,
                                              float* __restrict__ out,
                                              float* __restrict__ ssrc,
                                              float* __restrict__ sdst) {
    constexpr int VC = NOUT / 64;  // cols per lane (2 or 4)
    __shared__ float xs[32 * K];
    int row0 = blockIdx.x * 32;
    for (int idx = threadIdx.x; idx < 32 * K / 4; idx += 256) {
        int r = (idx * 4) / K, c = (idx * 4) % K;
        float4 v = make_float4(0.f, 0.f, 0.f, 0.f);
        if (row0 + r < N_NODES) v = *(const float4*)(x + (size_t)(row0 + r) * K + c);
        *(float4*)(xs + r * K + c) = v;
    }
    __syncthreads();
    int wave = threadIdx.x >> 6, lane = threadIdx.x & 63;
    int r0 = wave * 8;
    float acc[8][VC];
    #pragma unroll
    for (int r = 0; r < 8; ++r)
        #pragma unroll
        for (int c = 0; c < VC; ++c) acc[r][c] = 0.f;
    int colb = lane * VC;
    for (int k = 0; k < K; k += 4) {
        float4 xr[8];
        #pragma unroll
        for (int r = 0; r < 8; ++r) xr[r] = *(const float4*)(xs + (r0 + r) * K + k);
        #pragma unroll
        for (int kk = 0; kk < 4; ++kk) {
            float wv[VC];
            if constexpr (VC == 4) {
                float4 t = *(const float4*)(W + (size_t)(k + kk) * NOUT + colb);
                wv[0] = t.x; wv[1] = t.y; wv[2] = t.z; wv[3] = t.w;
            } else {
                float2 t = *(const float2*)(W + (size_t)(k + kk) * NOUT + colb);
                wv[0] = t.x; wv[1] = t.y;
            }
            #pragma unroll
            for (int r = 0; r < 8; ++r) {
                float xv = (kk == 0) ? xr[r].x : (kk == 1) ? xr[r].y
                         : (kk == 2) ? xr[r].z : xr[r].w;
                #pragma unroll
                for (int c = 0; c < VC; ++c) acc[r][c] += xv * wv[c];
            }
        }
    }
    float avs[VC], avd[VC];
    #pragma unroll
    for (int c = 0; c < VC; ++c) { avs[c] = asrc[colb + c]; avd[c] = adst[colb + c]; }
    int hd = lane >> 4, lg = lane & 15;
    #pragma unroll
    for (int r = 0; r < 8; ++r) {
        int row = row0 + r0 + r;
        if (row < N_NODES) {
            if constexpr (VC == 4) {
                *(float4*)(out + (size_t)row * NOUT + colb) =
                    make_float4(acc[r][0], acc[r][1], acc[r][2], acc[r][3]);
            } else {
                *(float2*)(out + (size_t)row * NOUT + colb) =
                    make_float2(acc[r][0], acc[r][1]);
            }
            float ps = 0.f, pd = 0.f;
            #pragma unroll
            for (int c = 0; c < VC; ++c) { ps += acc[r][c] * avs[c]; pd += acc[r][c] * avd[c]; }
            #pragma unroll
            for (int off = 1; off < 16; off <<= 1) {
                ps += __shfl_xor(ps, off);
                pd += __shfl_xor(pd, off);
            }
            if (lg == 0) {
                ssrc[row * NH + hd] = ps;
                sdst[row * NH + hd] = pd;
            }
        }
    }
}

// ---------------- normalized edge-softmax weights, all heads, once ----------------
// one wave per node; 16-lane group per head; alpha[e*NH+hd] = exp(e-m)/(den+1e-16)
__global__ __launch_bounds__(256) void alpha_k(const float* __restrict__ ssrc,
                                               const float* __restrict__ sdst,
                                               const int* __restrict__ row_ptr,
                                               const int* __restrict__ col,
                                               float* __restrict__ alpha) {
    int wv = threadIdx.x >> 6, lane = threadIdx.x & 63;
    int v = blockIdx.x * 4 + wv;
    if (v >= N_NODES) return;
    int hd = lane >> 4, lg = lane & 15;
    int beg = row_ptr[v], cnt = row_ptr[v + 1] - beg;
    float sdv = sdst[v * NH + hd];

    if (cnt <= 128) {
        float er[8];
        float m = -FLT_MAX;
        #pragma unroll
        for (int i = 0; i < 8; ++i) {
            int j = lg + i * 16;
            if (j < cnt) {
                int u = col[beg + j];
                float e = ssrc[u * NH + hd] + sdv;
                e = (e > 0.f) ? e : 0.2f * e;
                er[i] = e;
                m = fmaxf(m, e);
            }
        }
        #pragma unroll
        for (int off = 1; off < 16; off <<= 1) m = fmaxf(m, __shfl_xor(m, off));
        float den = 0.f;
        #pragma unroll
        for (int i = 0; i < 8; ++i) {
            int j = lg + i * 16;
            if (j < cnt) { float w = __expf(er[i] - m); er[i] = w; den += w; }
        }
        #pragma unroll
        for (int off = 1; off < 16; off <<= 1) den += __shfl_xor(den, off);
        float inv = 1.f / (den + 1e-16f);
        #pragma unroll
        for (int i = 0; i < 8; ++i) {
            int j = lg + i * 16;
            if (j < cnt) alpha[(size_t)(beg + j) * NH + hd] = er[i] * inv;
        }
    } else {
        // streaming 3-pass (practically never taken)
        float m = -FLT_MAX;
        for (int j = lg; j < cnt; j += 16) {
            int u = col[beg + j];
            float e = ssrc[u * NH + hd] + sdv;
            e = (e > 0.f) ? e : 0.2f * e;
            m = fmaxf(m, e);
        }
        #pragma unroll
        for (int off = 1; off < 16; off <<= 1) m = fmaxf(m, __shfl_xor(m, off));
        float den = 0.f;
        for (int j = lg; j < cnt; j += 16) {
            int u = col[beg + j];
            float e = ssrc[u * NH + hd] + sdv;
            e = (e > 0.f) ? e : 0.2f * e;
            den += __expf(e - m);
        }
        #pragma unroll
        for (int off = 1; off < 16; off <<= 1) den += __shfl_xor(den, off);
        float inv = 1.f / (den + 1e-16f);
        for (int j = lg; j < cnt; j += 16) {
            int u = col[beg + j];
            float e = ssrc[u * NH + hd] + sdv;
            e = (e > 0.f) ? e : 0.2f * e;
            alpha[(size_t)(beg + j) * NH + hd] = __expf(e - m) * inv;
        }
    }
}

// ---------------- XCD-sharded aggregation, vectorized, no LDS ----------------
// slice s = blockIdx % 8 (round-robin -> XCD s): SLICE=HFo/8 feats per block.
// LPN lanes per node, f4/lane; register-staged unroll-8 gather loop.
template<int HFo, int SLICE, int LPN>
__global__ __launch_bounds__(256) void agg2_k(const float* __restrict__ h,
                                              const float* __restrict__ alpha,
                                              const int* __restrict__ row_ptr,
                                              const int* __restrict__ col,
                                              const float* __restrict__ bias,
                                              float* __restrict__ out) {
    constexpr int Fo  = HFo / NH;
    constexpr int NPW = 64 / LPN;   // nodes per wave
    constexpr int NPB = 4 * NPW;    // nodes per block
    int s = blockIdx.x & 7;
    int g = blockIdx.x >> 3;
    int wv = threadIdx.x >> 6, lane = threadIdx.x & 63;
    int sub = lane / LPN, lq = lane % LPN;
    int v = g * NPB + wv * NPW + sub;
    if (v >= N_NODES) return;
    int f0 = s * SLICE + lq * 4;
    int hd = (s * SLICE) / Fo;      // uniform per block
    int beg = row_ptr[v], cnt = row_ptr[v + 1] - beg;
    const int*   cp = col + beg;
    const float* ap = alpha + (size_t)beg * NH + hd;

    f4 acc = {};
    int j = 0;
    for (; j + 8 <= cnt; j += 8) {
        int u[8]; float w[8]; f4 hv[8];
        #pragma unroll
        for (int i = 0; i < 8; ++i) u[i] = cp[j + i];
        #pragma unroll
        for (int i = 0; i < 8; ++i) w[i] = ap[(size_t)(j + i) * NH];
        #pragma unroll
        for (int i = 0; i < 8; ++i) hv[i] = *(const f4*)(h + (size_t)u[i] * HFo + f0);
        #pragma unroll
        for (int i = 0; i < 8; ++i) acc += w[i] * hv[i];
    }
    for (; j < cnt; ++j) {
        int u = cp[j];
        float w = ap[(size_t)j * NH];
        f4 hv = *(const f4*)(h + (size_t)u * HFo + f0);
        acc += w * hv;
    }
    f4 bv = *(const f4*)(bias + f0);
    f4 res = acc + bv;
    #pragma unroll
    for (int c = 0; c < 4; ++c) res[c] = fmaxf(res[c], 0.f);
    __builtin_nontemporal_store(res, (f4*)(out + (size_t)v * HFo + f0));
}

// ---------------- pooling (batch_index sorted -> run-length pre-agg) ----------------
__global__ void pool_k(const float* __restrict__ h, const int* __restrict__ batch,
                       float* __restrict__ gsum, float* __restrict__ gmax) {
    int f = threadIdx.x;  // 256
    int n0 = blockIdx.x * 32;
    int nend = min(n0 + 32, N_NODES);
    int cur = -1;
    float sa = 0.f, ma = 0.f;
    for (int n = n0; n < nend; ++n) {
        int g = batch[n];
        float val = h[(size_t)n * 256 + f];
        if (g != cur) {
            if (cur >= 0) {
                atomicAdd(&gsum[cur * 256 + f], sa);
                atomicMax((int*)&gmax[cur * 256 + f], __float_as_int(ma));
            }
            cur = g; sa = 0.f; ma = 0.f;
        }
        sa += val;
        ma = fmaxf(ma, val);
    }
    if (cur >= 0) {
        atomicAdd(&gsum[cur * 256 + f], sa);
        atomicMax((int*)&gmax[cur * 256 + f], __float_as_int(ma));
    }
}

// batch sorted -> per-graph count = boundary difference (binary search)
__global__ void gcnt_k(const int* __restrict__ batch, int* __restrict__ gcnt) {
    int g = threadIdx.x;  // 128 threads
    if (g >= NG) return;
    int lo = 0, hi = N_NODES;
    while (lo < hi) { int mid = (lo + hi) >> 1; if (batch[mid] < g) lo = mid + 1; else hi = mid; }
    int b0 = lo;
    lo = 0; hi = N_NODES;
    while (lo < hi) { int mid = (lo + hi) >> 1; if (batch[mid] < g + 1) lo = mid + 1; else hi = mid; }
    gcnt[g] = lo - b0;
}

__global__ void readout_k(const float* __restrict__ gsum, const float* __restrict__ gmax,
                          const int* __restrict__ gcnt, const float* __restrict__ Wout,
                          const float* __restrict__ bout, float* __restrict__ out) {
    int g = blockIdx.x, lane = threadIdx.x;
    float inv = 1.f / fmaxf((float)gcnt[g], 1.f);
    float acc[10];
    #pragma unroll
    for (int j = 0; j < 10; ++j) acc[j] = 0.f;
    for (int f = lane; f < 512; f += 64) {
        float p = (f < 256) ? gsum[g * 256 + f] * inv : gmax[g * 256 + (f - 256)];
        #pragma unroll
        for (int j = 0; j < 10; ++j) acc[j] += p * Wout[f * 10 + j];
    }
    #pragma unroll
    for (int j = 0; j < 10; ++j) {
        float a = acc[j];
        #pragma unroll
        for (int off = 32; off; off >>= 1) a += __shfl_xor(a, off);
        if (lane == 0) out[g * 10 + j] = a + bout[j];
    }
}

extern "C" void kernel_launch(void* const* d_in, const int* in_sizes, int n_in,
                              void* d_out, int out_size, void* d_ws, size_t ws_size,
                              hipStream_t stream) {
    const float* x    = (const float*)d_in[0];
    const int*   ei   = (const int*)d_in[1];
    const int*   batch= (const int*)d_in[2];
    const float* W0   = (const float*)d_in[3];
    const float* as0  = (const float*)d_in[4];
    const float* ad0  = (const float*)d_in[5];
    const float* b0   = (const float*)d_in[6];
    const float* W1   = (const float*)d_in[7];
    const float* as1  = (const float*)d_in[8];
    const float* ad1  = (const float*)d_in[9];
    const float* b1   = (const float*)d_in[10];
    const float* W2   = (const float*)d_in[11];
    const float* as2  = (const float*)d_in[12];
    const float* ad2  = (const float*)d_in[13];
    const float* b2   = (const float*)d_in[14];
    const float* Wout = (const float*)d_in[15];
    const float* bout = (const float*)d_in[16];
    float* out = (float*)d_out;

    char* ws = (char*)d_ws;
    size_t o = 0;
    auto take = [&](size_t bytes) { size_t r = o; o += (bytes + 255) & ~(size_t)255; return r; };
    size_t cnt_o  = take((size_t)N_NODES * 4);
    size_t gsum_o = take((size_t)NG * 256 * 4);
    size_t gmax_o = take((size_t)NG * 256 * 4);
    size_t gcnt_o = take((size_t)NG * 4);
    size_t zero_bytes = o;
    size_t rp_o   = take((size_t)(N_NODES + 1) * 4);
    size_t cur_o  = take((size_t)N_NODES * 4);
    size_t col_o  = take((size_t)E_TOT * 4);
    size_t ssrc_o = take((size_t)N_NODES * NH * 4);
    size_t sdst_o = take((size_t)N_NODES * NH * 4);
    size_t alp_o  = take((size_t)E_TOT * NH * 4);
    size_t bufA_o = take((size_t)N_NODES * 256 * 4);
    size_t bufB_o = take((size_t)N_NODES * 256 * 4);

    int*   cnt    = (int*)(ws + cnt_o);
    float* gsum   = (float*)(ws + gsum_o);
    float* gmax   = (float*)(ws + gmax_o);
    int*   gcnt   = (int*)(ws + gcnt_o);
    int*   row_ptr= (int*)(ws + rp_o);
    int*   cursor = (int*)(ws + cur_o);
    int*   col    = (int*)(ws + col_o);
    float* ssrc   = (float*)(ws + ssrc_o);
    float* sdst   = (float*)(ws + sdst_o);
    float* alpha  = (float*)(ws + alp_o);
    float* bufA   = (float*)(ws + bufA_o);
    float* bufB   = (float*)(ws + bufB_o);

    (void)hipMemsetAsync(ws, 0, zero_bytes, stream);

    count_dst_k<<<(E_TOT + 255) / 256, 256, 0, stream>>>(ei, cnt);
    scan_k<<<1, 1024, 0, stream>>>(cnt, row_ptr, cursor);
    fill_k<<<(E_TOT + 255) / 256, 256, 0, stream>>>(ei, cursor, col);

    int gemm_grid  = (N_NODES + 31) / 32;
    int alpha_grid = (N_NODES + 3) / 4;
    // agg2 grids: 8 slices x node groups. HFo=128: SLICE=16,LPN=4 -> NPB=64;
    //             HFo=256: SLICE=32,LPN=8 -> NPB=32.
    int agg128_grid = 8 * ((N_NODES + 63) / 64);
    int agg256_grid = 8 * ((N_NODES + 31) / 32);

    // layer 0: 128 -> H4*Fo32 (128)
    gemm_k<128, 128><<<gemm_grid, 256, 0, stream>>>(x, W0, as0, ad0, bufA, ssrc, sdst);
    alpha_k<<<alpha_grid, 256, 0, stream>>>(ssrc, sdst, row_ptr, col, alpha);
    agg2_k<128, 16, 4><<<agg128_grid, 256, 0, stream>>>(bufA, alpha, row_ptr, col, b0, bufB);

    // layer 1: 128 -> H4*Fo64 (256)
    gemm_k<128, 256><<<gemm_grid, 256, 0, stream>>>(bufB, W1, as1, ad1, bufA, ssrc, sdst);
    alpha_k<<<alpha_grid, 256, 0, stream>>>(ssrc, sdst, row_ptr, col, alpha);
    agg2_k<256, 32, 8><<<agg256_grid, 256, 0, stream>>>(bufA, alpha, row_ptr, col, b1, bufB);

    // layer 2: 256 -> H4*Fo64 (256)
    gemm_k<256, 256><<<gemm_grid, 256, 0, stream>>>(bufB, W2, as2, ad2, bufA, ssrc, sdst);
    alpha_k<<<alpha_grid, 256, 0, stream>>>(ssrc, sdst, row_ptr, col, alpha);
    agg2_k<256, 32, 8><<<agg256_grid, 256, 0, stream>>>(bufA, alpha, row_ptr, col, b2, bufB);

    // pooling + readout
    pool_k<<<(N_NODES + 31) / 32, 256, 0, stream>>>(bufB, batch, gsum, gmax);
    gcnt_k<<<1, 128, 0, stream>>>(batch, gcnt);
    readout_k<<<NG, 64, 0, stream>>>(gsum, gmax, gcnt, Wout, bout, out);
}